// Round 4
// baseline (2280.132 us; speedup 1.0000x reference)
//
#include <hip/hip_runtime.h>
#include <hip/hip_bf16.h>
#include <cstddef>

#define BS_     32
#define NUM_R_  10
#define NUM_P_  36
#define SL_Q_   20
#define IMG_F_  2048
#define TDIM_   600
#define LSTM_   512
#define CAT_    2648

typedef unsigned short ushort_t;
typedef __attribute__((ext_vector_type(8))) short short8;
typedef __attribute__((ext_vector_type(4))) float f32x4;

__device__ __forceinline__ ushort_t f2bf(float f) {
  union { float f; unsigned int u; } v; v.f = f;
  unsigned int r = v.u + 0x7fff + ((v.u >> 16) & 1);
  return (ushort_t)(r >> 16);
}
__device__ __forceinline__ float bf2f(ushort_t u) {
  union { unsigned int u; float f; } v; v.u = ((unsigned int)u) << 16;
  return v.f;
}

// ---------------------------------------------------------------------------
// Elementwise f32 -> bf16 (n % 4 == 0)
// ---------------------------------------------------------------------------
__global__ __launch_bounds__(256) void convert_bf16_k(
    const float* __restrict__ in, ushort_t* __restrict__ out, int n4)
{
  int i = blockIdx.x * 256 + threadIdx.x;
  if (i >= n4) return;
  float4 v = reinterpret_cast<const float4*>(in)[i];
  ushort4 o;
  o.x = f2bf(v.x); o.y = f2bf(v.y); o.z = f2bf(v.z); o.w = f2bf(v.w);
  reinterpret_cast<ushort4*>(out)[i] = o;
}

// ---------------------------------------------------------------------------
// Transpose + convert: in rows [r0, r0+R) x C f32  ->  out (C x R) bf16
// ---------------------------------------------------------------------------
__global__ __launch_bounds__(256) void transpose_bf16_k(
    const float* __restrict__ in, ushort_t* __restrict__ out,
    int r0, int R, int C)
{
  __shared__ float tile[64][65];
  const int t = threadIdx.x;
  const int lc = t & 63, g = t >> 6;       // g in 0..3
  const int rbase = blockIdx.y * 64, cbase = blockIdx.x * 64;
#pragma unroll
  for (int i = 0; i < 16; ++i) {
    int lr = g + 4 * i;
    int rr = rbase + lr, cc = cbase + lc;
    tile[lr][lc] = (rr < R && cc < C) ? in[(size_t)(r0 + rr) * C + cc] : 0.f;
  }
  __syncthreads();
#pragma unroll
  for (int i = 0; i < 16; ++i) {
    int wr = g + 4 * i;                     // output row = input col
    int oc = cbase + wr, orr = rbase + lc;  // out[oc][orr]
    if (oc < C && orr < R)
      out[(size_t)oc * R + orr] = f2bf(tile[lc][wr]);
  }
}

// ---------------------------------------------------------------------------
// MFMA GEMM: A (M x K) bf16 row-major, BT (N x K) bf16 row-major.
// 128x128 tile, 4 waves (2x2), each wave 64x64 = 4x4 frags of 16x16x32.
// mode 0: outf[m,n] = acc                      (himg)
// mode 1: outb[m,n] = bf16(relu(acc+D+bias)),  A rows remapped by round r
// mode 2: outf[remap(m),n] = relu(acc+bias),   out rows remapped by round r
// ---------------------------------------------------------------------------
__global__ __launch_bounds__(256) void mfma_gemm_k(
    const ushort_t* __restrict__ A, const ushort_t* __restrict__ BT,
    const float* __restrict__ bias, const float* __restrict__ D,
    float* __restrict__ outf, ushort_t* __restrict__ outb,
    int M, int K, int N, int mode, int r)
{
  __shared__ ushort_t Als[128 * 40];
  __shared__ ushort_t Bls[128 * 40];
  const int tid = threadIdx.x;
  const int lane = tid & 63, w = tid >> 6;
  const int wr = w >> 1, wc = w & 1;
  const int m0 = blockIdx.y * 128, n0 = blockIdx.x * 128;

  // staging thread constants: slot s = tid + rep*256; row = s>>2, seg = s&3
  size_t a_off[2]; int a_ok[2]; int b_row[2]; int seg_[2]; int row_[2];
#pragma unroll
  for (int rep = 0; rep < 2; ++rep) {
    int s = tid + rep * 256;
    int row = s >> 2, seg = s & 3;
    row_[rep] = row; seg_[rep] = seg;
    int gm = m0 + row;
    a_ok[rep] = (gm < M);
    size_t arow;
    if (mode == 1) {
      int ib = gm / NUM_P_, p = gm - ib * NUM_P_;
      arow = (size_t)((ib * NUM_R_ + r) * NUM_P_ + p);
    } else arow = (size_t)gm;
    a_off[rep] = arow * (size_t)K;
    b_row[rep] = n0 + row;
  }

  f32x4 acc[4][4] = {};

  for (int k0 = 0; k0 < K; k0 += 32) {
#pragma unroll
    for (int rep = 0; rep < 2; ++rep) {
      int kk = k0 + seg_[rep] * 8;
      uint4 av = make_uint4(0u, 0u, 0u, 0u);
      if (a_ok[rep] && kk < K)
        av = *reinterpret_cast<const uint4*>(&A[a_off[rep] + kk]);
      *reinterpret_cast<uint4*>(&Als[row_[rep] * 40 + seg_[rep] * 8]) = av;
      uint4 bv = make_uint4(0u, 0u, 0u, 0u);
      if (b_row[rep] < N && kk < K)
        bv = *reinterpret_cast<const uint4*>(&BT[(size_t)b_row[rep] * K + kk]);
      *reinterpret_cast<uint4*>(&Bls[row_[rep] * 40 + seg_[rep] * 8]) = bv;
    }
    __syncthreads();

    short8 af[4], bfv[4];
#pragma unroll
    for (int i = 0; i < 4; ++i)
      af[i] = *reinterpret_cast<const short8*>(
          &Als[(wr * 64 + i * 16 + (lane & 15)) * 40 + (lane >> 4) * 8]);
#pragma unroll
    for (int j = 0; j < 4; ++j)
      bfv[j] = *reinterpret_cast<const short8*>(
          &Bls[(wc * 64 + j * 16 + (lane & 15)) * 40 + (lane >> 4) * 8]);
#pragma unroll
    for (int i = 0; i < 4; ++i)
#pragma unroll
      for (int j = 0; j < 4; ++j)
        acc[i][j] = __builtin_amdgcn_mfma_f32_16x16x32_bf16(af[i], bfv[j], acc[i][j], 0, 0, 0);
    __syncthreads();
  }

  // epilogue: D[row][col], col = lane&15, row = (lane>>4)*4 + reg
  const int crow = (lane >> 4) * 4, ccol = lane & 15;
#pragma unroll
  for (int i = 0; i < 4; ++i) {
#pragma unroll
    for (int j = 0; j < 4; ++j) {
#pragma unroll
      for (int q = 0; q < 4; ++q) {
        int gm = m0 + wr * 64 + i * 16 + crow + q;
        int gn = n0 + wc * 64 + j * 16 + ccol;
        if (gm >= M || gn >= N) continue;
        float v = acc[i][j][q];
        if (mode == 0) {
          outf[(size_t)gm * N + gn] = v;
        } else if (mode == 1) {
          v += D[(size_t)gm * N + gn] + bias[gn];
          outb[(size_t)gm * N + gn] = f2bf(v > 0.f ? v : 0.f);
        } else {
          v += bias[gn];
          int ib = gm / NUM_P_, p = gm - ib * NUM_P_;
          size_t orow = (size_t)((ib * NUM_R_ + r) * NUM_P_ + p);
          outf[orow * N + gn] = v > 0.f ? v : 0.f;
        }
      }
    }
  }
}

// ---------------------------------------------------------------------------
// Gated MFMA GEMM: out = bf16( tanh(A@Wy + by) * leaky_relu(A@Wg + bg) )
// A (M x K) bf16, ByT/BgT (N x K) bf16, N = 512. Tile 128x64, wave 64x32.
// ---------------------------------------------------------------------------
__global__ __launch_bounds__(256) void gated_mfma_k(
    const ushort_t* __restrict__ A,
    const ushort_t* __restrict__ ByT, const ushort_t* __restrict__ BgT,
    const float* __restrict__ by, const float* __restrict__ bg,
    ushort_t* __restrict__ out, int M, int K, int N)
{
  __shared__ ushort_t Als[128 * 40];
  __shared__ ushort_t Bls[2][64 * 40];
  const int tid = threadIdx.x;
  const int lane = tid & 63, w = tid >> 6;
  const int wr = w >> 1, wc = w & 1;
  const int m0 = blockIdx.y * 128, n0 = blockIdx.x * 64;

  int rowA[2], segA[2], okA[2];
#pragma unroll
  for (int rep = 0; rep < 2; ++rep) {
    int s = tid + rep * 256;
    rowA[rep] = s >> 2; segA[rep] = s & 3;
    okA[rep] = (m0 + rowA[rep]) < M;
  }
  const int rowB = tid >> 2, segB = tid & 3;   // 256 slots cover 64 rows x 4 segs
  const int okB = (n0 + rowB) < N;

  f32x4 accy[4][2] = {}, accg[4][2] = {};

  for (int k0 = 0; k0 < K; k0 += 32) {
#pragma unroll
    for (int rep = 0; rep < 2; ++rep) {
      int kk = k0 + segA[rep] * 8;
      uint4 av = make_uint4(0u, 0u, 0u, 0u);
      if (okA[rep] && kk < K)
        av = *reinterpret_cast<const uint4*>(&A[(size_t)(m0 + rowA[rep]) * K + kk]);
      *reinterpret_cast<uint4*>(&Als[rowA[rep] * 40 + segA[rep] * 8]) = av;
    }
    {
      int kk = k0 + segB * 8;
      uint4 yv = make_uint4(0u, 0u, 0u, 0u), gv = yv;
      if (okB && kk < K) {
        yv = *reinterpret_cast<const uint4*>(&ByT[(size_t)(n0 + rowB) * K + kk]);
        gv = *reinterpret_cast<const uint4*>(&BgT[(size_t)(n0 + rowB) * K + kk]);
      }
      *reinterpret_cast<uint4*>(&Bls[0][rowB * 40 + segB * 8]) = yv;
      *reinterpret_cast<uint4*>(&Bls[1][rowB * 40 + segB * 8]) = gv;
    }
    __syncthreads();

    short8 af[4], byf[2], bgf[2];
#pragma unroll
    for (int i = 0; i < 4; ++i)
      af[i] = *reinterpret_cast<const short8*>(
          &Als[(wr * 64 + i * 16 + (lane & 15)) * 40 + (lane >> 4) * 8]);
#pragma unroll
    for (int j = 0; j < 2; ++j) {
      int boff = (wc * 32 + j * 16 + (lane & 15)) * 40 + (lane >> 4) * 8;
      byf[j] = *reinterpret_cast<const short8*>(&Bls[0][boff]);
      bgf[j] = *reinterpret_cast<const short8*>(&Bls[1][boff]);
    }
#pragma unroll
    for (int i = 0; i < 4; ++i)
#pragma unroll
      for (int j = 0; j < 2; ++j) {
        accy[i][j] = __builtin_amdgcn_mfma_f32_16x16x32_bf16(af[i], byf[j], accy[i][j], 0, 0, 0);
        accg[i][j] = __builtin_amdgcn_mfma_f32_16x16x32_bf16(af[i], bgf[j], accg[i][j], 0, 0, 0);
      }
    __syncthreads();
  }

  const int crow = (lane >> 4) * 4, ccol = lane & 15;
#pragma unroll
  for (int i = 0; i < 4; ++i)
#pragma unroll
    for (int j = 0; j < 2; ++j)
#pragma unroll
      for (int q = 0; q < 4; ++q) {
        int gm = m0 + wr * 64 + i * 16 + crow + q;
        int gn = n0 + wc * 32 + j * 16 + ccol;
        if (gm >= M || gn >= N) continue;
        float y = tanhf(accy[i][j][q] + by[gn]);
        float g = accg[i][j][q] + bg[gn];
        g = (g > 0.f) ? g : 0.01f * g;
        out[(size_t)gm * N + gn] = f2bf(y * g);
      }
}

// ---------------------------------------------------------------------------
// Fused attention (bf16 feats): scores, mask, softmax(20), PV with raw topic.
// ---------------------------------------------------------------------------
__global__ __launch_bounds__(256) void attn_fuse_k(
    const ushort_t* __restrict__ v_feat,     // (32,36,512) bf16
    const ushort_t* __restrict__ topic_feat, // (320,20,512) bf16
    const float* __restrict__ topic_raw,     // (320,20,600) f32
    const int*   __restrict__ qnp,           // (320,20)
    ushort_t* __restrict__ vt_att)           // (320,36,600) bf16
{
  const int b  = blockIdx.x;
  const int ib = b / NUM_R_;
  __shared__ float tr[SL_Q_][TDIM_];
  __shared__ float msk[SL_Q_];

  const int tid = threadIdx.x;
  {
    const float4* g = reinterpret_cast<const float4*>(topic_raw + (size_t)b * SL_Q_ * TDIM_);
    float4* s = reinterpret_cast<float4*>(&tr[0][0]);
    for (int i = tid; i < SL_Q_ * TDIM_ / 4; i += 256) s[i] = g[i];
  }
  if (tid < SL_Q_) msk[tid] = (float)qnp[b * SL_Q_ + tid];
  __syncthreads();

  const int wave = tid >> 6, lane = tid & 63;
  const ushort_t* tf_b = topic_feat + (size_t)b * SL_Q_ * LSTM_;

  for (int p = wave; p < NUM_P_; p += 4) {
    const ushort_t* v = v_feat + ((size_t)ib * NUM_P_ + p) * LSTM_;
    float vr[8];
#pragma unroll
    for (int k = 0; k < 8; ++k) vr[k] = bf2f(v[lane + 64 * k]);

    float sc[SL_Q_];
#pragma unroll
    for (int s = 0; s < SL_Q_; ++s) {
      const ushort_t* tfs = tf_b + (size_t)s * LSTM_;
      float acc = 0.f;
#pragma unroll
      for (int k = 0; k < 8; ++k) acc += vr[k] * bf2f(tfs[lane + 64 * k]);
#pragma unroll
      for (int off = 32; off > 0; off >>= 1) acc += __shfl_xor(acc, off, 64);
      sc[s] = acc;
    }
    float mx = -1e30f;
#pragma unroll
    for (int s = 0; s < SL_Q_; ++s) {
      float m = msk[s];
      sc[s] = sc[s] * m + (m - 1.f) * 10000.f;
      mx = fmaxf(mx, sc[s]);
    }
    float sum = 0.f;
#pragma unroll
    for (int s = 0; s < SL_Q_; ++s) { sc[s] = expf(sc[s] - mx); sum += sc[s]; }
    const float inv = 1.f / sum;

    ushort_t* outp = vt_att + ((size_t)b * NUM_P_ + p) * TDIM_;
    for (int t = lane; t < TDIM_; t += 64) {
      float acc = 0.f;
#pragma unroll
      for (int s = 0; s < SL_Q_; ++s) acc += sc[s] * tr[s][t];
      outp[t] = f2bf(acc * inv);
    }
  }
}

// ---------------------------------------------------------------------------
extern "C" void kernel_launch(void* const* d_in, const int* in_sizes, int n_in,
                              void* d_out, int out_size, void* d_ws, size_t ws_size,
                              hipStream_t stream) {
  const float* img    = (const float*)d_in[0];
  const float* topic  = (const float*)d_in[1];
  const int*   qnp    = (const int*)d_in[2];
  const float* Wy_img = (const float*)d_in[3];
  const float* by_img = (const float*)d_in[4];
  const float* Wg_img = (const float*)d_in[5];
  const float* bg_img = (const float*)d_in[6];
  const float* Wy_t   = (const float*)d_in[7];
  const float* by_t   = (const float*)d_in[8];
  const float* Wg_t   = (const float*)d_in[9];
  const float* bg_t   = (const float*)d_in[10];
  const float* W1     = (const float*)d_in[11];
  const float* b1     = (const float*)d_in[12];
  const float* W2     = (const float*)d_in[13];
  const float* b2     = (const float*)d_in[14];
  float* out = (float*)d_out;

  // workspace allocator (256B aligned)
  char* base = (char*)d_ws;
  size_t off = 0;
  auto alloc = [&](size_t bytes) {
    void* p = base + off;
    off += (bytes + 255) & ~(size_t)255;
    return p;
  };
  ushort_t* img_bf    = (ushort_t*)alloc((size_t)1152 * 2048 * 2);
  ushort_t* topic_bf  = (ushort_t*)alloc((size_t)6400 * 600 * 2);
  ushort_t* WyT_img   = (ushort_t*)alloc((size_t)512 * 2048 * 2);
  ushort_t* WgT_img   = (ushort_t*)alloc((size_t)512 * 2048 * 2);
  ushort_t* WyT_t     = (ushort_t*)alloc((size_t)512 * 600 * 2);
  ushort_t* WgT_t     = (ushort_t*)alloc((size_t)512 * 600 * 2);
  ushort_t* W1T_top   = (ushort_t*)alloc((size_t)2648 * 2048 * 2);
  ushort_t* W1T_bot   = (ushort_t*)alloc((size_t)2648 * 600 * 2);
  ushort_t* W2T       = (ushort_t*)alloc((size_t)2048 * 2648 * 2);
  ushort_t* v_feat    = (ushort_t*)alloc((size_t)1152 * 512 * 2);
  ushort_t* topic_ft  = (ushort_t*)alloc((size_t)6400 * 512 * 2);
  ushort_t* vt_att    = (ushort_t*)alloc((size_t)320 * 36 * 600 * 2);
  float*    himg      = (float*)alloc((size_t)1152 * 2648 * 4);
  ushort_t* h1_bf     = (ushort_t*)alloc((size_t)1152 * 2648 * 2);
  (void)ws_size;

  const dim3 blk(256);

  // converts
  convert_bf16_k<<<dim3((1152 * 2048 / 4 + 255) / 256), blk, 0, stream>>>(img, img_bf, 1152 * 2048 / 4);
  convert_bf16_k<<<dim3((6400 * 600 / 4 + 255) / 256), blk, 0, stream>>>(topic, topic_bf, 6400 * 600 / 4);

  // weight transposes (in R' x C -> out C x R')
  auto tgrid = [](int R, int C) { return dim3((C + 63) / 64, (R + 63) / 64); };
  transpose_bf16_k<<<tgrid(2048, 512), blk, 0, stream>>>(Wy_img, WyT_img, 0, 2048, 512);
  transpose_bf16_k<<<tgrid(2048, 512), blk, 0, stream>>>(Wg_img, WgT_img, 0, 2048, 512);
  transpose_bf16_k<<<tgrid(600, 512), blk, 0, stream>>>(Wy_t, WyT_t, 0, 600, 512);
  transpose_bf16_k<<<tgrid(600, 512), blk, 0, stream>>>(Wg_t, WgT_t, 0, 600, 512);
  transpose_bf16_k<<<tgrid(2048, 2648), blk, 0, stream>>>(W1, W1T_top, 0, 2048, 2648);
  transpose_bf16_k<<<tgrid(600, 2648), blk, 0, stream>>>(W1, W1T_bot, 2048, 600, 2648);
  transpose_bf16_k<<<tgrid(2648, 2048), blk, 0, stream>>>(W2, W2T, 0, 2648, 2048);

  // gated transforms (MFMA)
  gated_mfma_k<<<dim3(512 / 64, 1152 / 128), blk, 0, stream>>>(
      img_bf, WyT_img, WgT_img, by_img, bg_img, v_feat, 1152, 2048, 512);
  gated_mfma_k<<<dim3(512 / 64, 6400 / 128), blk, 0, stream>>>(
      topic_bf, WyT_t, WgT_t, by_t, bg_t, topic_ft, 6400, 600, 512);

  // attention -> vt_att (bf16)
  attn_fuse_k<<<dim3(BS_ * NUM_R_), blk, 0, stream>>>(v_feat, topic_ft, topic, qnp, vt_att);

  // himg = img @ W1top (mode 0, f32)
  mfma_gemm_k<<<dim3((CAT_ + 127) / 128, 1152 / 128), blk, 0, stream>>>(
      img_bf, W1T_top, nullptr, nullptr, himg, nullptr, 1152, 2048, CAT_, 0, 0);

  // per-round MLP
  for (int r = 0; r < NUM_R_; ++r) {
    mfma_gemm_k<<<dim3((CAT_ + 127) / 128, 1152 / 128), blk, 0, stream>>>(
        vt_att, W1T_bot, b1, himg, nullptr, h1_bf, 1152, 600, CAT_, 1, r);
    mfma_gemm_k<<<dim3(IMG_F_ / 128, 1152 / 128), blk, 0, stream>>>(
        h1_bf, W2T, b2, nullptr, out, nullptr, 1152, CAT_, IMG_F_, 2, r);
  }
}

// Round 7
// 869.324 us; speedup vs baseline: 2.6229x; 2.6229x over previous
//
#include <hip/hip_runtime.h>
#include <hip/hip_bf16.h>
#include <cstddef>

#define BS_     32
#define NUM_R_  10
#define NUM_P_  36
#define SL_Q_   20
#define IMG_F_  2048
#define TDIM_   600
#define LSTM_   512
#define CAT_    2648

typedef unsigned short ushort_t;
typedef __attribute__((ext_vector_type(8))) short short8;
typedef __attribute__((ext_vector_type(4))) float f32x4;

__device__ __forceinline__ ushort_t f2bf(float f) {
  union { float f; unsigned int u; } v; v.f = f;
  unsigned int r = v.u + 0x7fff + ((v.u >> 16) & 1);
  return (ushort_t)(r >> 16);
}
__device__ __forceinline__ float bf2f(ushort_t u) {
  union { unsigned int u; float f; } v; v.u = ((unsigned int)u) << 16;
  return v.f;
}

// ---------------------------------------------------------------------------
// Elementwise f32 -> bf16 (n % 4 == 0)
// ---------------------------------------------------------------------------
__global__ __launch_bounds__(256) void convert_bf16_k(
    const float* __restrict__ in, ushort_t* __restrict__ out, int n4)
{
  int i = blockIdx.x * 256 + threadIdx.x;
  if (i >= n4) return;
  float4 v = reinterpret_cast<const float4*>(in)[i];
  ushort4 o;
  o.x = f2bf(v.x); o.y = f2bf(v.y); o.z = f2bf(v.z); o.w = f2bf(v.w);
  reinterpret_cast<ushort4*>(out)[i] = o;
}

// ---------------------------------------------------------------------------
// Transpose + convert: in rows [r0, r0+R) x C f32  ->  out (C x R) bf16
// ---------------------------------------------------------------------------
__global__ __launch_bounds__(256) void transpose_bf16_k(
    const float* __restrict__ in, ushort_t* __restrict__ out,
    int r0, int R, int C)
{
  __shared__ float tile[64][65];
  const int t = threadIdx.x;
  const int lc = t & 63, g = t >> 6;       // g in 0..3
  const int rbase = blockIdx.y * 64, cbase = blockIdx.x * 64;
#pragma unroll
  for (int i = 0; i < 16; ++i) {
    int lr = g + 4 * i;
    int rr = rbase + lr, cc = cbase + lc;
    tile[lr][lc] = (rr < R && cc < C) ? in[(size_t)(r0 + rr) * C + cc] : 0.f;
  }
  __syncthreads();
#pragma unroll
  for (int i = 0; i < 16; ++i) {
    int wr = g + 4 * i;                     // output row = input col
    int oc = cbase + wr, orr = rbase + lc;  // out[oc][orr]
    if (oc < C && orr < R)
      out[(size_t)oc * R + orr] = f2bf(tile[lc][wr]);
  }
}

// ---------------------------------------------------------------------------
// MFMA GEMM: A (M x K) bf16 row-major, BT (N x K) bf16 row-major.
// 128x128 tile, 4 waves (2x2), each wave 64x64 = 4x4 frags of 16x16x32.
// mode 0: outf[m,n] = acc                                   (himg)
// mode 1: outb[m,n] = bf16(relu(acc + D[dmap(base+m)] + bias))  (batched h1)
//         dmap(g) = (g/360)*36 + g%36   (himg row for global row g)
// mode 2: outf[m,n] = relu(acc + bias)   (outf pre-offset by caller)
// ---------------------------------------------------------------------------
__global__ __launch_bounds__(256) void mfma_gemm_k(
    const ushort_t* __restrict__ A, const ushort_t* __restrict__ BT,
    const float* __restrict__ bias, const float* __restrict__ D,
    float* __restrict__ outf, ushort_t* __restrict__ outb,
    int M, int K, int N, int mode, int base)
{
  __shared__ ushort_t Als[128 * 40];
  __shared__ ushort_t Bls[128 * 40];
  const int tid = threadIdx.x;
  const int lane = tid & 63, w = tid >> 6;
  const int wr = w >> 1, wc = w & 1;
  const int m0 = blockIdx.y * 128, n0 = blockIdx.x * 128;

  // staging thread constants: slot s = tid + rep*256; row = s>>2, seg = s&3
  size_t a_off[2]; int a_ok[2]; int b_row[2]; int seg_[2]; int row_[2];
#pragma unroll
  for (int rep = 0; rep < 2; ++rep) {
    int s = tid + rep * 256;
    int row = s >> 2, seg = s & 3;
    row_[rep] = row; seg_[rep] = seg;
    int gm = m0 + row;
    a_ok[rep] = (gm < M);
    a_off[rep] = (size_t)gm * (size_t)K;
    b_row[rep] = n0 + row;
  }

  f32x4 acc[4][4] = {};

  for (int k0 = 0; k0 < K; k0 += 32) {
#pragma unroll
    for (int rep = 0; rep < 2; ++rep) {
      int kk = k0 + seg_[rep] * 8;
      uint4 av = make_uint4(0u, 0u, 0u, 0u);
      if (a_ok[rep] && kk < K)
        av = *reinterpret_cast<const uint4*>(&A[a_off[rep] + kk]);
      *reinterpret_cast<uint4*>(&Als[row_[rep] * 40 + seg_[rep] * 8]) = av;
      uint4 bv = make_uint4(0u, 0u, 0u, 0u);
      if (b_row[rep] < N && kk < K)
        bv = *reinterpret_cast<const uint4*>(&BT[(size_t)b_row[rep] * K + kk]);
      *reinterpret_cast<uint4*>(&Bls[row_[rep] * 40 + seg_[rep] * 8]) = bv;
    }
    __syncthreads();

    short8 af[4], bfv[4];
#pragma unroll
    for (int i = 0; i < 4; ++i)
      af[i] = *reinterpret_cast<const short8*>(
          &Als[(wr * 64 + i * 16 + (lane & 15)) * 40 + (lane >> 4) * 8]);
#pragma unroll
    for (int j = 0; j < 4; ++j)
      bfv[j] = *reinterpret_cast<const short8*>(
          &Bls[(wc * 64 + j * 16 + (lane & 15)) * 40 + (lane >> 4) * 8]);
#pragma unroll
    for (int i = 0; i < 4; ++i)
#pragma unroll
      for (int j = 0; j < 4; ++j)
        acc[i][j] = __builtin_amdgcn_mfma_f32_16x16x32_bf16(af[i], bfv[j], acc[i][j], 0, 0, 0);
    __syncthreads();
  }

  // epilogue: C/D frag layout col = lane&15, row = (lane>>4)*4 + reg
  const int crow = (lane >> 4) * 4, ccol = lane & 15;
#pragma unroll
  for (int i = 0; i < 4; ++i) {
#pragma unroll
    for (int j = 0; j < 4; ++j) {
#pragma unroll
      for (int q = 0; q < 4; ++q) {
        int gm = m0 + wr * 64 + i * 16 + crow + q;
        int gn = n0 + wc * 64 + j * 16 + ccol;
        if (gm >= M || gn >= N) continue;
        float v = acc[i][j][q];
        if (mode == 0) {
          outf[(size_t)gm * N + gn] = v;
        } else if (mode == 1) {
          int g = base + gm;
          int drow = (g / 360) * 36 + (g % 36);
          v += D[(size_t)drow * N + gn] + bias[gn];
          outb[(size_t)gm * N + gn] = f2bf(v > 0.f ? v : 0.f);
        } else {
          v += bias[gn];
          outf[(size_t)gm * N + gn] = v > 0.f ? v : 0.f;
        }
      }
    }
  }
}

// ---------------------------------------------------------------------------
// Gated MFMA GEMM: out = bf16( tanh(A@Wy + by) * leaky_relu(A@Wg + bg) )
// A (M x K) bf16, ByT/BgT (N x K) bf16, N = 512. Tile 128x64, wave 64x32.
// ---------------------------------------------------------------------------
__global__ __launch_bounds__(256) void gated_mfma_k(
    const ushort_t* __restrict__ A,
    const ushort_t* __restrict__ ByT, const ushort_t* __restrict__ BgT,
    const float* __restrict__ by, const float* __restrict__ bg,
    ushort_t* __restrict__ out, int M, int K, int N)
{
  __shared__ ushort_t Als[128 * 40];
  __shared__ ushort_t Bls[2][64 * 40];
  const int tid = threadIdx.x;
  const int lane = tid & 63, w = tid >> 6;
  const int wr = w >> 1, wc = w & 1;
  const int m0 = blockIdx.y * 128, n0 = blockIdx.x * 64;

  int rowA[2], segA[2], okA[2];
#pragma unroll
  for (int rep = 0; rep < 2; ++rep) {
    int s = tid + rep * 256;
    rowA[rep] = s >> 2; segA[rep] = s & 3;
    okA[rep] = (m0 + rowA[rep]) < M;
  }
  const int rowB = tid >> 2, segB = tid & 3;   // 256 slots cover 64 rows x 4 segs
  const int okB = (n0 + rowB) < N;

  f32x4 accy[4][2] = {}, accg[4][2] = {};

  for (int k0 = 0; k0 < K; k0 += 32) {
#pragma unroll
    for (int rep = 0; rep < 2; ++rep) {
      int kk = k0 + segA[rep] * 8;
      uint4 av = make_uint4(0u, 0u, 0u, 0u);
      if (okA[rep] && kk < K)
        av = *reinterpret_cast<const uint4*>(&A[(size_t)(m0 + rowA[rep]) * K + kk]);
      *reinterpret_cast<uint4*>(&Als[rowA[rep] * 40 + segA[rep] * 8]) = av;
    }
    {
      int kk = k0 + segB * 8;
      uint4 yv = make_uint4(0u, 0u, 0u, 0u), gv = yv;
      if (okB && kk < K) {
        yv = *reinterpret_cast<const uint4*>(&ByT[(size_t)(n0 + rowB) * K + kk]);
        gv = *reinterpret_cast<const uint4*>(&BgT[(size_t)(n0 + rowB) * K + kk]);
      }
      *reinterpret_cast<uint4*>(&Bls[0][rowB * 40 + segB * 8]) = yv;
      *reinterpret_cast<uint4*>(&Bls[1][rowB * 40 + segB * 8]) = gv;
    }
    __syncthreads();

    short8 af[4], byf[2], bgf[2];
#pragma unroll
    for (int i = 0; i < 4; ++i)
      af[i] = *reinterpret_cast<const short8*>(
          &Als[(wr * 64 + i * 16 + (lane & 15)) * 40 + (lane >> 4) * 8]);
#pragma unroll
    for (int j = 0; j < 2; ++j) {
      int boff = (wc * 32 + j * 16 + (lane & 15)) * 40 + (lane >> 4) * 8;
      byf[j] = *reinterpret_cast<const short8*>(&Bls[0][boff]);
      bgf[j] = *reinterpret_cast<const short8*>(&Bls[1][boff]);
    }
#pragma unroll
    for (int i = 0; i < 4; ++i)
#pragma unroll
      for (int j = 0; j < 2; ++j) {
        accy[i][j] = __builtin_amdgcn_mfma_f32_16x16x32_bf16(af[i], byf[j], accy[i][j], 0, 0, 0);
        accg[i][j] = __builtin_amdgcn_mfma_f32_16x16x32_bf16(af[i], bgf[j], accg[i][j], 0, 0, 0);
      }
    __syncthreads();
  }

  const int crow = (lane >> 4) * 4, ccol = lane & 15;
#pragma unroll
  for (int i = 0; i < 4; ++i)
#pragma unroll
    for (int j = 0; j < 2; ++j)
#pragma unroll
      for (int q = 0; q < 4; ++q) {
        int gm = m0 + wr * 64 + i * 16 + crow + q;
        int gn = n0 + wc * 32 + j * 16 + ccol;
        if (gm >= M || gn >= N) continue;
        float y = tanhf(accy[i][j][q] + by[gn]);
        float g = accg[i][j][q] + bg[gn];
        g = (g > 0.f) ? g : 0.01f * g;
        out[(size_t)gm * N + gn] = f2bf(y * g);
      }
}

// ---------------------------------------------------------------------------
// Fused attention (bf16 feats): scores, mask, softmax(20), PV with raw topic.
// ---------------------------------------------------------------------------
__global__ __launch_bounds__(256) void attn_fuse_k(
    const ushort_t* __restrict__ v_feat,     // (32,36,512) bf16
    const ushort_t* __restrict__ topic_feat, // (320,20,512) bf16
    const float* __restrict__ topic_raw,     // (320,20,600) f32
    const int*   __restrict__ qnp,           // (320,20)
    ushort_t* __restrict__ vt_att)           // (320,36,600) bf16
{
  const int b  = blockIdx.x;
  const int ib = b / NUM_R_;
  __shared__ float tr[SL_Q_][TDIM_];
  __shared__ float msk[SL_Q_];

  const int tid = threadIdx.x;
  {
    const float4* g = reinterpret_cast<const float4*>(topic_raw + (size_t)b * SL_Q_ * TDIM_);
    float4* s = reinterpret_cast<float4*>(&tr[0][0]);
    for (int i = tid; i < SL_Q_ * TDIM_ / 4; i += 256) s[i] = g[i];
  }
  if (tid < SL_Q_) msk[tid] = (float)qnp[b * SL_Q_ + tid];
  __syncthreads();

  const int wave = tid >> 6, lane = tid & 63;
  const ushort_t* tf_b = topic_feat + (size_t)b * SL_Q_ * LSTM_;

  for (int p = wave; p < NUM_P_; p += 4) {
    const ushort_t* v = v_feat + ((size_t)ib * NUM_P_ + p) * LSTM_;
    float vr[8];
#pragma unroll
    for (int k = 0; k < 8; ++k) vr[k] = bf2f(v[lane + 64 * k]);

    float sc[SL_Q_];
#pragma unroll
    for (int s = 0; s < SL_Q_; ++s) {
      const ushort_t* tfs = tf_b + (size_t)s * LSTM_;
      float acc = 0.f;
#pragma unroll
      for (int k = 0; k < 8; ++k) acc += vr[k] * bf2f(tfs[lane + 64 * k]);
#pragma unroll
      for (int off = 32; off > 0; off >>= 1) acc += __shfl_xor(acc, off, 64);
      sc[s] = acc;
    }
    float mx = -1e30f;
#pragma unroll
    for (int s = 0; s < SL_Q_; ++s) {
      float m = msk[s];
      sc[s] = sc[s] * m + (m - 1.f) * 10000.f;
      mx = fmaxf(mx, sc[s]);
    }
    float sum = 0.f;
#pragma unroll
    for (int s = 0; s < SL_Q_; ++s) { sc[s] = expf(sc[s] - mx); sum += sc[s]; }
    const float inv = 1.f / sum;

    ushort_t* outp = vt_att + ((size_t)b * NUM_P_ + p) * TDIM_;
    for (int t = lane; t < TDIM_; t += 64) {
      float acc = 0.f;
#pragma unroll
      for (int s = 0; s < SL_Q_; ++s) acc += sc[s] * tr[s][t];
      outp[t] = f2bf(acc * inv);
    }
  }
}

// ---------------------------------------------------------------------------
extern "C" void kernel_launch(void* const* d_in, const int* in_sizes, int n_in,
                              void* d_out, int out_size, void* d_ws, size_t ws_size,
                              hipStream_t stream) {
  const float* img    = (const float*)d_in[0];
  const float* topic  = (const float*)d_in[1];
  const int*   qnp    = (const int*)d_in[2];
  const float* Wy_img = (const float*)d_in[3];
  const float* by_img = (const float*)d_in[4];
  const float* Wg_img = (const float*)d_in[5];
  const float* bg_img = (const float*)d_in[6];
  const float* Wy_t   = (const float*)d_in[7];
  const float* by_t   = (const float*)d_in[8];
  const float* Wg_t   = (const float*)d_in[9];
  const float* bg_t   = (const float*)d_in[10];
  const float* W1     = (const float*)d_in[11];
  const float* b1     = (const float*)d_in[12];
  const float* W2     = (const float*)d_in[13];
  const float* b2     = (const float*)d_in[14];
  float* out = (float*)d_out;

  // --- workspace layout (manually aliased; peak ~76.5 MB) ---
  // Region X [offset 0): dead after himg GEMM; h1 chunk aliases it afterwards.
  char* base = (char*)d_ws;
  size_t off = 0;
  auto alloc = [&](size_t bytes) {
    void* p = base + off;
    off += (bytes + 255) & ~(size_t)255;
    return p;
  };
  // region X (36.4 MB): consumed by phases A-D only
  ushort_t* img_bf    = (ushort_t*)alloc((size_t)1152 * 2048 * 2);
  ushort_t* topic_bf  = (ushort_t*)alloc((size_t)6400 * 600 * 2);
  ushort_t* WyT_img   = (ushort_t*)alloc((size_t)512 * 2048 * 2);
  ushort_t* WgT_img   = (ushort_t*)alloc((size_t)512 * 2048 * 2);
  ushort_t* WyT_t     = (ushort_t*)alloc((size_t)512 * 600 * 2);
  ushort_t* WgT_t     = (ushort_t*)alloc((size_t)512 * 600 * 2);
  ushort_t* W1T_top   = (ushort_t*)alloc((size_t)2648 * 2048 * 2);
  ushort_t* v_feat    = (ushort_t*)alloc((size_t)1152 * 512 * 2);
  ushort_t* topic_ft  = (ushort_t*)alloc((size_t)6400 * 512 * 2);
  size_t regionX_end = off;
  // persistent region
  ushort_t* W1T_bot   = (ushort_t*)alloc((size_t)2648 * 600 * 2);
  ushort_t* W2T       = (ushort_t*)alloc((size_t)2048 * 2648 * 2);
  ushort_t* vt_att    = (ushort_t*)alloc((size_t)320 * 36 * 600 * 2);
  float*    himg      = (float*)alloc((size_t)1152 * 2648 * 4);
  // h1 chunk (2 chunks of 5760 rows): aliases region X (30.5 MB <= 36.4 MB)
  ushort_t* h1c       = (ushort_t*)base;
  (void)regionX_end; (void)ws_size;

  const dim3 blk(256);

  // --- phase A: converts + weight transposes ---
  convert_bf16_k<<<dim3((1152 * 2048 / 4 + 255) / 256), blk, 0, stream>>>(img, img_bf, 1152 * 2048 / 4);
  convert_bf16_k<<<dim3((6400 * 600 / 4 + 255) / 256), blk, 0, stream>>>(topic, topic_bf, 6400 * 600 / 4);

  auto tgrid = [](int R, int C) { return dim3((C + 63) / 64, (R + 63) / 64); };
  transpose_bf16_k<<<tgrid(2048, 512), blk, 0, stream>>>(Wy_img, WyT_img, 0, 2048, 512);
  transpose_bf16_k<<<tgrid(2048, 512), blk, 0, stream>>>(Wg_img, WgT_img, 0, 2048, 512);
  transpose_bf16_k<<<tgrid(600, 512), blk, 0, stream>>>(Wy_t, WyT_t, 0, 600, 512);
  transpose_bf16_k<<<tgrid(600, 512), blk, 0, stream>>>(Wg_t, WgT_t, 0, 600, 512);
  transpose_bf16_k<<<tgrid(2048, 2648), blk, 0, stream>>>(W1, W1T_top, 0, 2048, 2648);
  transpose_bf16_k<<<tgrid(600, 2648), blk, 0, stream>>>(W1, W1T_bot, 2048, 600, 2648);
  transpose_bf16_k<<<tgrid(2648, 2048), blk, 0, stream>>>(W2, W2T, 0, 2648, 2048);

  // --- phase B: gated transforms (MFMA) ---
  gated_mfma_k<<<dim3(512 / 64, 1152 / 128), blk, 0, stream>>>(
      img_bf, WyT_img, WgT_img, by_img, bg_img, v_feat, 1152, 2048, 512);
  gated_mfma_k<<<dim3(512 / 64, 6400 / 128), blk, 0, stream>>>(
      topic_bf, WyT_t, WgT_t, by_t, bg_t, topic_ft, 6400, 600, 512);

  // --- phase C: attention -> vt_att (bf16) ---
  attn_fuse_k<<<dim3(BS_ * NUM_R_), blk, 0, stream>>>(v_feat, topic_ft, topic, qnp, vt_att);

  // --- phase D: himg = img @ W1top (mode 0, f32) ---
  mfma_gemm_k<<<dim3((CAT_ + 127) / 128, 1152 / 128), blk, 0, stream>>>(
      img_bf, W1T_top, nullptr, nullptr, himg, nullptr, 1152, 2048, CAT_, 0, 0);

  // --- phases E/F: batched MLP over all rounds, 2 chunks of 5760 rows ---
  // vt_att rows (ib*10+r)*36+p == h1/out rows: no A remap needed.
  for (int c = 0; c < 2; ++c) {
    const int mbase = c * 5760;
    mfma_gemm_k<<<dim3((CAT_ + 127) / 128, 5760 / 128), blk, 0, stream>>>(
        vt_att + (size_t)mbase * TDIM_, W1T_bot, b1, himg, nullptr, h1c,
        5760, TDIM_, CAT_, 1, mbase);
    mfma_gemm_k<<<dim3(IMG_F_ / 128, 5760 / 128), blk, 0, stream>>>(
        h1c, W2T, b2, nullptr, out + (size_t)mbase * IMG_F_, nullptr,
        5760, CAT_, IMG_F_, 2, 0);
  }
}

// Round 8
// 618.213 us; speedup vs baseline: 3.6883x; 1.4062x over previous
//
#include <hip/hip_runtime.h>
#include <hip/hip_bf16.h>
#include <cstddef>
#include <cstdint>

#define BS_     32
#define NUM_R_  10
#define NUM_P_  36
#define SL_Q_   20
#define IMG_F_  2048
#define TDIM_   600
#define TDIMP_  608     // 600 padded to %32==0... (608=19*32)
#define LSTM_   512
#define CAT_    2648
#define CATP_K  2656    // 2648 padded for K staging (83*32)
#define CATP_R  2688    // 2648 padded for B-row tiles (21*128)

typedef unsigned short ushort_t;
typedef __attribute__((ext_vector_type(8))) short short8;
typedef __attribute__((ext_vector_type(4))) float f32x4;

__device__ __forceinline__ ushort_t f2bf(float f) {
  union { float f; unsigned int u; } v; v.f = f;
  unsigned int r = v.u + 0x7fff + ((v.u >> 16) & 1);
  return (ushort_t)(r >> 16);
}
__device__ __forceinline__ float bf2f(ushort_t u) {
  union { unsigned int u; float f; } v; v.u = ((unsigned int)u) << 16;
  return v.f;
}

// async global->LDS, 16B per lane; LDS dest is wave-uniform base + lane*16
typedef __attribute__((address_space(1))) const unsigned int as1_uint;
typedef __attribute__((address_space(3))) unsigned int as3_uint;
__device__ __forceinline__ void gl_lds16(const ushort_t* g, ushort_t* l) {
  __builtin_amdgcn_global_load_lds((as1_uint*)g, (as3_uint*)l, 16, 0, 0);
}

// ---------------------------------------------------------------------------
// Elementwise f32 -> bf16 (n % 4 == 0, no padding)
// ---------------------------------------------------------------------------
__global__ __launch_bounds__(256) void convert_bf16_k(
    const float* __restrict__ in, ushort_t* __restrict__ out, int n4)
{
  int i = blockIdx.x * 256 + threadIdx.x;
  if (i >= n4) return;
  float4 v = reinterpret_cast<const float4*>(in)[i];
  ushort4 o;
  o.x = f2bf(v.x); o.y = f2bf(v.y); o.z = f2bf(v.z); o.w = f2bf(v.w);
  reinterpret_cast<ushort4*>(out)[i] = o;
}

// ---------------------------------------------------------------------------
// f32 (rows x C) -> bf16 (rows x Cp), zero-padded columns [C, Cp)
// ---------------------------------------------------------------------------
__global__ __launch_bounds__(256) void convert_pad_k(
    const float* __restrict__ in, ushort_t* __restrict__ out,
    int rows, int C, int Cp)
{
  int npc = Cp >> 2;
  int i = blockIdx.x * 256 + threadIdx.x;
  if (i >= rows * npc) return;
  int row = i / npc, c4 = (i - row * npc) << 2;
  ushort4 o = make_ushort4(0, 0, 0, 0);
  if (c4 < C) {
    float4 v = *reinterpret_cast<const float4*>(&in[(size_t)row * C + c4]);
    o.x = f2bf(v.x); o.y = f2bf(v.y); o.z = f2bf(v.z); o.w = f2bf(v.w);
  }
  *reinterpret_cast<ushort4*>(&out[(size_t)row * Cp + c4]) = o;
}

// ---------------------------------------------------------------------------
// Transpose+convert+pad: in rows [r0,r0+R) x C f32 -> out (Cp x Rp) bf16,
// ld = Rp, zero outside (C x R).
// ---------------------------------------------------------------------------
__global__ __launch_bounds__(256) void transpose_pad_k(
    const float* __restrict__ in, ushort_t* __restrict__ out,
    int r0, int R, int C, int Rp, int Cp)
{
  __shared__ float tile[64][65];
  const int t = threadIdx.x;
  const int lc = t & 63, g = t >> 6;
  const int rbase = blockIdx.y * 64, cbase = blockIdx.x * 64;
#pragma unroll
  for (int i = 0; i < 16; ++i) {
    int lr = g + 4 * i;
    int rr = rbase + lr, cc = cbase + lc;
    tile[lr][lc] = (rr < R && cc < C) ? in[(size_t)(r0 + rr) * C + cc] : 0.f;
  }
  __syncthreads();
#pragma unroll
  for (int i = 0; i < 16; ++i) {
    int wr2 = g + 4 * i;
    int oc = cbase + wr2, orr = rbase + lc;
    if (oc < Cp && orr < Rp)
      out[(size_t)oc * Rp + orr] = f2bf(tile[lc][wr2]);
  }
}

// ---------------------------------------------------------------------------
// MFMA GEMM, global_load_lds staging. A (M x Kp), BT (Nrows x Kp), all
// zero-padded so staging needs NO bounds checks. M%128==0, Kp%32==0.
// LDS linear [128][32] shorts (64B rows).
// mode 0: outf[m,n]=acc                          (gn<N)
// mode 1: outb[m,n]=bf16(relu(acc+D[dmap]+bias)) cols [N,ldOutb) zeroed
// mode 2: outf[m,n]=relu(acc+bias)
// ---------------------------------------------------------------------------
__global__ __launch_bounds__(256) void mfma_gemm_k(
    const ushort_t* __restrict__ A, const ushort_t* __restrict__ BT,
    const float* __restrict__ bias, const float* __restrict__ D,
    float* __restrict__ outf, ushort_t* __restrict__ outb,
    int M, int Kp, int N, int ldOutb, int mode, int base)
{
  __shared__ ushort_t Als[128 * 32];
  __shared__ ushort_t Bls[128 * 32];
  const int tid = threadIdx.x;
  const int lane = tid & 63, w = tid >> 6;
  const int wr = w >> 1, wc = w & 1;
  const int m0 = blockIdx.y * 128, n0 = blockIdx.x * 128;

  // staging: wave w covers rows [32w,32w+32) of each tile, 2 issues of 16 rows
  const int srow = lane >> 2;          // 0..15
  const int scol = (lane & 3) * 8;     // shorts
  const ushort_t* gA0 = A + (size_t)(m0 + w * 32 + srow) * Kp + scol;
  const ushort_t* gA1 = gA0 + (size_t)16 * Kp;
  const ushort_t* gB0 = BT + (size_t)(n0 + w * 32 + srow) * Kp + scol;
  const ushort_t* gB1 = gB0 + (size_t)16 * Kp;
  ushort_t* lA0 = &Als[(w * 32) * 32];
  ushort_t* lA1 = &Als[(w * 32 + 16) * 32];
  ushort_t* lB0 = &Bls[(w * 32) * 32];
  ushort_t* lB1 = &Bls[(w * 32 + 16) * 32];

  f32x4 acc[4][4] = {};

  for (int k0 = 0; k0 < Kp; k0 += 32) {
    gl_lds16(gA0 + k0, lA0);
    gl_lds16(gA1 + k0, lA1);
    gl_lds16(gB0 + k0, lB0);
    gl_lds16(gB1 + k0, lB1);
    __syncthreads();   // compiler emits vmcnt(0) drain before s_barrier

    short8 af[4], bfv[4];
#pragma unroll
    for (int i = 0; i < 4; ++i)
      af[i] = *reinterpret_cast<const short8*>(
          &Als[(wr * 64 + i * 16 + (lane & 15)) * 32 + (lane >> 4) * 8]);
#pragma unroll
    for (int j = 0; j < 4; ++j)
      bfv[j] = *reinterpret_cast<const short8*>(
          &Bls[(wc * 64 + j * 16 + (lane & 15)) * 32 + (lane >> 4) * 8]);
#pragma unroll
    for (int i = 0; i < 4; ++i)
#pragma unroll
      for (int j = 0; j < 4; ++j)
        acc[i][j] = __builtin_amdgcn_mfma_f32_16x16x32_bf16(af[i], bfv[j], acc[i][j], 0, 0, 0);
    __syncthreads();
  }

  // epilogue: C/D frag layout col=lane&15, row=(lane>>4)*4+reg
  const int crow = (lane >> 4) * 4, ccol = lane & 15;
#pragma unroll
  for (int i = 0; i < 4; ++i) {
#pragma unroll
    for (int j = 0; j < 4; ++j) {
#pragma unroll
      for (int q = 0; q < 4; ++q) {
        int gm = m0 + wr * 64 + i * 16 + crow + q;
        int gn = n0 + wc * 64 + j * 16 + ccol;
        float v = acc[i][j][q];
        if (mode == 0) {
          if (gn < N) outf[(size_t)gm * N + gn] = v;
        } else if (mode == 1) {
          if (gn < ldOutb) {
            float vv = 0.f;
            if (gn < N) {
              int g = base + gm;
              int drow = (g / 360) * 36 + (g % 36);
              vv = v + D[(size_t)drow * CAT_ + gn] + bias[gn];
              vv = vv > 0.f ? vv : 0.f;
            }
            outb[(size_t)gm * ldOutb + gn] = f2bf(vv);
          }
        } else {
          if (gn < N) {
            float vv = v + bias[gn];
            outf[(size_t)gm * N + gn] = vv > 0.f ? vv : 0.f;
          }
        }
      }
    }
  }
}

// ---------------------------------------------------------------------------
// Gated MFMA GEMM: out = bf16( tanh(A@Wy+by) * leaky_relu(A@Wg+bg) )
// A (M x Kp) padded, ByT/BgT (512 x Kp) padded. Tile 128x64, global_load_lds.
// ---------------------------------------------------------------------------
__global__ __launch_bounds__(256) void gated_mfma_k(
    const ushort_t* __restrict__ A,
    const ushort_t* __restrict__ ByT, const ushort_t* __restrict__ BgT,
    const float* __restrict__ by, const float* __restrict__ bg,
    ushort_t* __restrict__ out, int M, int Kp, int N)
{
  __shared__ ushort_t Als[128 * 32];
  __shared__ ushort_t Bls[2][64 * 32];
  const int tid = threadIdx.x;
  const int lane = tid & 63, w = tid >> 6;
  const int wr = w >> 1, wc = w & 1;
  const int m0 = blockIdx.y * 128, n0 = blockIdx.x * 64;

  const int srow = lane >> 2;
  const int scol = (lane & 3) * 8;
  const ushort_t* gA0 = A + (size_t)(m0 + w * 32 + srow) * Kp + scol;
  const ushort_t* gA1 = gA0 + (size_t)16 * Kp;
  // wave w stages B-matrix (w>>1), rows [(w&1)*32, +32)
  const ushort_t* gBm = (w >> 1) ? BgT : ByT;
  const ushort_t* gB0 = gBm + (size_t)(n0 + (w & 1) * 32 + srow) * Kp + scol;
  const ushort_t* gB1 = gB0 + (size_t)16 * Kp;
  ushort_t* lA0 = &Als[(w * 32) * 32];
  ushort_t* lA1 = &Als[(w * 32 + 16) * 32];
  ushort_t* lB0 = &Bls[w >> 1][((w & 1) * 32) * 32];
  ushort_t* lB1 = &Bls[w >> 1][((w & 1) * 32 + 16) * 32];

  f32x4 accy[4][2] = {}, accg[4][2] = {};

  for (int k0 = 0; k0 < Kp; k0 += 32) {
    gl_lds16(gA0 + k0, lA0);
    gl_lds16(gA1 + k0, lA1);
    gl_lds16(gB0 + k0, lB0);
    gl_lds16(gB1 + k0, lB1);
    __syncthreads();

    short8 af[4], byf[2], bgf[2];
#pragma unroll
    for (int i = 0; i < 4; ++i)
      af[i] = *reinterpret_cast<const short8*>(
          &Als[(wr * 64 + i * 16 + (lane & 15)) * 32 + (lane >> 4) * 8]);
#pragma unroll
    for (int j = 0; j < 2; ++j) {
      int boff = (wc * 32 + j * 16 + (lane & 15)) * 32 + (lane >> 4) * 8;
      byf[j] = *reinterpret_cast<const short8*>(&Bls[0][boff]);
      bgf[j] = *reinterpret_cast<const short8*>(&Bls[1][boff]);
    }
#pragma unroll
    for (int i = 0; i < 4; ++i)
#pragma unroll
      for (int j = 0; j < 2; ++j) {
        accy[i][j] = __builtin_amdgcn_mfma_f32_16x16x32_bf16(af[i], byf[j], accy[i][j], 0, 0, 0);
        accg[i][j] = __builtin_amdgcn_mfma_f32_16x16x32_bf16(af[i], bgf[j], accg[i][j], 0, 0, 0);
      }
    __syncthreads();
  }

  const int crow = (lane >> 4) * 4, ccol = lane & 15;
#pragma unroll
  for (int i = 0; i < 4; ++i)
#pragma unroll
    for (int j = 0; j < 2; ++j)
#pragma unroll
      for (int q = 0; q < 4; ++q) {
        int gm = m0 + wr * 64 + i * 16 + crow + q;
        int gn = n0 + wc * 32 + j * 16 + ccol;
        if (gm >= M || gn >= N) continue;
        float y = tanhf(accy[i][j][q] + by[gn]);
        float g = accg[i][j][q] + bg[gn];
        g = (g > 0.f) ? g : 0.01f * g;
        out[(size_t)gm * N + gn] = f2bf(y * g);
      }
}

// ---------------------------------------------------------------------------
// Fused attention: scores, mask, softmax(20), PV. vt_att padded to 608 cols.
// ---------------------------------------------------------------------------
__global__ __launch_bounds__(256) void attn_fuse_k(
    const ushort_t* __restrict__ v_feat,     // (32,36,512) bf16
    const ushort_t* __restrict__ topic_feat, // (320,20,512) bf16
    const float* __restrict__ topic_raw,     // (320,20,600) f32
    const int*   __restrict__ qnp,           // (320,20)
    ushort_t* __restrict__ vt_att)           // (320,36,608) bf16, cols 600.. = 0
{
  const int b  = blockIdx.x;
  const int ib = b / NUM_R_;
  __shared__ float tr[SL_Q_][TDIM_];
  __shared__ float msk[SL_Q_];

  const int tid = threadIdx.x;
  {
    const float4* g = reinterpret_cast<const float4*>(topic_raw + (size_t)b * SL_Q_ * TDIM_);
    float4* s = reinterpret_cast<float4*>(&tr[0][0]);
    for (int i = tid; i < SL_Q_ * TDIM_ / 4; i += 256) s[i] = g[i];
  }
  if (tid < SL_Q_) msk[tid] = (float)qnp[b * SL_Q_ + tid];
  __syncthreads();

  const int wave = tid >> 6, lane = tid & 63;
  const ushort_t* tf_b = topic_feat + (size_t)b * SL_Q_ * LSTM_;

  for (int p = wave; p < NUM_P_; p += 4) {
    const ushort_t* v = v_feat + ((size_t)ib * NUM_P_ + p) * LSTM_;
    float vr[8];
#pragma unroll
    for (int k = 0; k < 8; ++k) vr[k] = bf2f(v[lane + 64 * k]);

    float sc[SL_Q_];
#pragma unroll
    for (int s = 0; s < SL_Q_; ++s) {
      const ushort_t* tfs = tf_b + (size_t)s * LSTM_;
      float acc = 0.f;
#pragma unroll
      for (int k = 0; k < 8; ++k) acc += vr[k] * bf2f(tfs[lane + 64 * k]);
#pragma unroll
      for (int off = 32; off > 0; off >>= 1) acc += __shfl_xor(acc, off, 64);
      sc[s] = acc;
    }
    float mx = -1e30f;
#pragma unroll
    for (int s = 0; s < SL_Q_; ++s) {
      float m = msk[s];
      sc[s] = sc[s] * m + (m - 1.f) * 10000.f;
      mx = fmaxf(mx, sc[s]);
    }
    float sum = 0.f;
#pragma unroll
    for (int s = 0; s < SL_Q_; ++s) { sc[s] = expf(sc[s] - mx); sum += sc[s]; }
    const float inv = 1.f / sum;

    ushort_t* outp = vt_att + ((size_t)b * NUM_P_ + p) * TDIMP_;
    for (int t = lane; t < TDIMP_; t += 64) {
      float acc = 0.f;
      if (t < TDIM_) {
#pragma unroll
        for (int s = 0; s < SL_Q_; ++s) acc += sc[s] * tr[s][t];
        acc *= inv;
      }
      outp[t] = f2bf(t < TDIM_ ? acc : 0.f);
    }
  }
}

// ---------------------------------------------------------------------------
extern "C" void kernel_launch(void* const* d_in, const int* in_sizes, int n_in,
                              void* d_out, int out_size, void* d_ws, size_t ws_size,
                              hipStream_t stream) {
  const float* img    = (const float*)d_in[0];
  const float* topic  = (const float*)d_in[1];
  const int*   qnp    = (const int*)d_in[2];
  const float* Wy_img = (const float*)d_in[3];
  const float* by_img = (const float*)d_in[4];
  const float* Wg_img = (const float*)d_in[5];
  const float* bg_img = (const float*)d_in[6];
  const float* Wy_t   = (const float*)d_in[7];
  const float* by_t   = (const float*)d_in[8];
  const float* Wg_t   = (const float*)d_in[9];
  const float* bg_t   = (const float*)d_in[10];
  const float* W1     = (const float*)d_in[11];
  const float* b1     = (const float*)d_in[12];
  const float* W2     = (const float*)d_in[13];
  const float* b2     = (const float*)d_in[14];
  float* out = (float*)d_out;

  // --- workspace (manually aliased; peak ~77 MB) ---
  char* base = (char*)d_ws;
  size_t off = 0;
  auto alloc = [&](size_t bytes) {
    void* p = base + off;
    off += (bytes + 255) & ~(size_t)255;
    return p;
  };
  // region X (~36.7 MB): dead after phase D; h1c aliases it
  ushort_t* img_bf    = (ushort_t*)alloc((size_t)1152 * 2048 * 2);
  ushort_t* topic_bf  = (ushort_t*)alloc((size_t)6400 * TDIMP_ * 2);
  ushort_t* WyT_img   = (ushort_t*)alloc((size_t)512 * 2048 * 2);
  ushort_t* WgT_img   = (ushort_t*)alloc((size_t)512 * 2048 * 2);
  ushort_t* WyT_t     = (ushort_t*)alloc((size_t)512 * TDIMP_ * 2);
  ushort_t* WgT_t     = (ushort_t*)alloc((size_t)512 * TDIMP_ * 2);
  ushort_t* W1T_top   = (ushort_t*)alloc((size_t)CATP_R * 2048 * 2);
  ushort_t* v_feat    = (ushort_t*)alloc((size_t)1152 * 512 * 2);
  ushort_t* topic_ft  = (ushort_t*)alloc((size_t)6400 * 512 * 2);
  // persistent region
  ushort_t* W1T_bot   = (ushort_t*)alloc((size_t)CATP_R * TDIMP_ * 2);
  ushort_t* W2T       = (ushort_t*)alloc((size_t)2048 * CATP_K * 2);
  ushort_t* vt_att    = (ushort_t*)alloc((size_t)11520 * TDIMP_ * 2);
  float*    himg      = (float*)alloc((size_t)1152 * CAT_ * 4);
  // h1 chunk (5760 x 2656 bf16 = 30.6 MB) aliases region X
  ushort_t* h1c       = (ushort_t*)base;
  (void)ws_size;

  const dim3 blk(256);

  // --- phase A: converts + weight transposes (zero-padded) ---
  convert_bf16_k<<<dim3((1152 * 2048 / 4 + 255) / 256), blk, 0, stream>>>(
      img, img_bf, 1152 * 2048 / 4);
  convert_pad_k<<<dim3((6400 * (TDIMP_ / 4) + 255) / 256), blk, 0, stream>>>(
      topic, topic_bf, 6400, TDIM_, TDIMP_);

  transpose_pad_k<<<dim3(8, 32), blk, 0, stream>>>(Wy_img, WyT_img, 0, 2048, 512, 2048, 512);
  transpose_pad_k<<<dim3(8, 32), blk, 0, stream>>>(Wg_img, WgT_img, 0, 2048, 512, 2048, 512);
  transpose_pad_k<<<dim3(8, 10), blk, 0, stream>>>(Wy_t, WyT_t, 0, 600, 512, TDIMP_, 512);
  transpose_pad_k<<<dim3(8, 10), blk, 0, stream>>>(Wg_t, WgT_t, 0, 600, 512, TDIMP_, 512);
  transpose_pad_k<<<dim3(42, 32), blk, 0, stream>>>(W1, W1T_top, 0, 2048, CAT_, 2048, CATP_R);
  transpose_pad_k<<<dim3(42, 10), blk, 0, stream>>>(W1, W1T_bot, 2048, 600, CAT_, TDIMP_, CATP_R);
  transpose_pad_k<<<dim3(32, 42), blk, 0, stream>>>(W2, W2T, 0, CAT_, 2048, CATP_K, 2048);

  // --- phase B: gated transforms ---
  gated_mfma_k<<<dim3(8, 9), blk, 0, stream>>>(
      img_bf, WyT_img, WgT_img, by_img, bg_img, v_feat, 1152, 2048, 512);
  gated_mfma_k<<<dim3(8, 50), blk, 0, stream>>>(
      topic_bf, WyT_t, WgT_t, by_t, bg_t, topic_ft, 6400, TDIMP_, 512);

  // --- phase C: attention -> vt_att (padded 608) ---
  attn_fuse_k<<<dim3(BS_ * NUM_R_), blk, 0, stream>>>(v_feat, topic_ft, topic, qnp, vt_att);

  // --- phase D: himg = img @ W1top (f32, 1152 x 2648) ---
  mfma_gemm_k<<<dim3(21, 9), blk, 0, stream>>>(
      img_bf, W1T_top, nullptr, nullptr, himg, nullptr, 1152, 2048, CAT_, 0, 0, 0);

  // --- phases E/F: batched MLP, 2 chunks of 5760 rows ---
  for (int c = 0; c < 2; ++c) {
    const int mbase = c * 5760;
    mfma_gemm_k<<<dim3(21, 45), blk, 0, stream>>>(
        vt_att + (size_t)mbase * TDIMP_, W1T_bot, b1, himg, nullptr, h1c,
        5760, TDIMP_, CAT_, CATP_K, 1, mbase);
    mfma_gemm_k<<<dim3(16, 45), blk, 0, stream>>>(
        h1c, W2T, b2, nullptr, out + (size_t)mbase * IMG_F_, nullptr,
        5760, CATP_K, 2048, 0, 2, 0);
  }
}

// Round 9
// 585.695 us; speedup vs baseline: 3.8930x; 1.0555x over previous
//
#include <hip/hip_runtime.h>
#include <hip/hip_bf16.h>
#include <cstddef>
#include <cstdint>

#define BS_     32
#define NUM_R_  10
#define NUM_P_  36
#define SL_Q_   20
#define IMG_F_  2048
#define TDIM_   600
#define TDIMP_  640     // 600 padded to %64==0 (10 x 64)
#define LSTM_   512
#define CAT_    2648
#define CATP_K  2688    // 2648 padded to %64==0 (42 x 64); also %128 for row tiles
#define CATP_R  2688

typedef unsigned short ushort_t;
typedef __attribute__((ext_vector_type(8))) short short8;
typedef __attribute__((ext_vector_type(4))) float f32x4;

__device__ __forceinline__ ushort_t f2bf(float f) {
  union { float f; unsigned int u; } v; v.f = f;
  unsigned int r = v.u + 0x7fff + ((v.u >> 16) & 1);
  return (ushort_t)(r >> 16);
}
__device__ __forceinline__ float bf2f(ushort_t u) {
  union { unsigned int u; float f; } v; v.u = ((unsigned int)u) << 16;
  return v.f;
}

// async global->LDS, 16B per lane; LDS dest = wave-uniform base + lane*16
typedef __attribute__((address_space(1))) const unsigned int as1_uint;
typedef __attribute__((address_space(3))) unsigned int as3_uint;
__device__ __forceinline__ void gl_lds16(const ushort_t* g, ushort_t* l) {
  __builtin_amdgcn_global_load_lds((as1_uint*)g, (as3_uint*)l, 16, 0, 0);
}

// ---------------------------------------------------------------------------
// Elementwise f32 -> bf16 (n % 4 == 0)
// ---------------------------------------------------------------------------
__global__ __launch_bounds__(256) void convert_bf16_k(
    const float* __restrict__ in, ushort_t* __restrict__ out, int n4)
{
  int i = blockIdx.x * 256 + threadIdx.x;
  if (i >= n4) return;
  float4 v = reinterpret_cast<const float4*>(in)[i];
  ushort4 o;
  o.x = f2bf(v.x); o.y = f2bf(v.y); o.z = f2bf(v.z); o.w = f2bf(v.w);
  reinterpret_cast<ushort4*>(out)[i] = o;
}

// ---------------------------------------------------------------------------
// f32 (rows x C) -> bf16 (rows x Cp), zero-padded columns [C, Cp)
// ---------------------------------------------------------------------------
__global__ __launch_bounds__(256) void convert_pad_k(
    const float* __restrict__ in, ushort_t* __restrict__ out,
    int rows, int C, int Cp)
{
  int npc = Cp >> 2;
  int i = blockIdx.x * 256 + threadIdx.x;
  if (i >= rows * npc) return;
  int row = i / npc, c4 = (i - row * npc) << 2;
  ushort4 o = make_ushort4(0, 0, 0, 0);
  if (c4 < C) {
    float4 v = *reinterpret_cast<const float4*>(&in[(size_t)row * C + c4]);
    o.x = f2bf(v.x); o.y = f2bf(v.y); o.z = f2bf(v.z); o.w = f2bf(v.w);
  }
  *reinterpret_cast<ushort4*>(&out[(size_t)row * Cp + c4]) = o;
}

// ---------------------------------------------------------------------------
// Transpose+convert+pad: in rows [r0,r0+R) x C f32 -> out (Cp x Rp) bf16,
// ld = Rp, zero outside (C x R).
// ---------------------------------------------------------------------------
__global__ __launch_bounds__(256) void transpose_pad_k(
    const float* __restrict__ in, ushort_t* __restrict__ out,
    int r0, int R, int C, int Rp, int Cp)
{
  __shared__ float tile[64][65];
  const int t = threadIdx.x;
  const int lc = t & 63, g = t >> 6;
  const int rbase = blockIdx.y * 64, cbase = blockIdx.x * 64;
#pragma unroll
  for (int i = 0; i < 16; ++i) {
    int lr = g + 4 * i;
    int rr = rbase + lr, cc = cbase + lc;
    tile[lr][lc] = (rr < R && cc < C) ? in[(size_t)(r0 + rr) * C + cc] : 0.f;
  }
  __syncthreads();
#pragma unroll
  for (int i = 0; i < 16; ++i) {
    int wr2 = g + 4 * i;
    int oc = cbase + wr2, orr = rbase + lc;
    if (oc < Cp && orr < Rp)
      out[(size_t)oc * Rp + orr] = f2bf(tile[lc][wr2]);
  }
}

// ---------------------------------------------------------------------------
// shared compute helper: 8x ds_read_b128 + 16 MFMA on a 128x128 quadrant set
// ---------------------------------------------------------------------------
__device__ __forceinline__ void gemm_comp(
    const ushort_t* __restrict__ Als, const ushort_t* __restrict__ Bls,
    int wr, int wc, int lane, f32x4 (&acc)[4][4])
{
  short8 af[4], bfv[4];
#pragma unroll
  for (int i = 0; i < 4; ++i)
    af[i] = *reinterpret_cast<const short8*>(
        &Als[(wr * 64 + i * 16 + (lane & 15)) * 32 + (lane >> 4) * 8]);
#pragma unroll
  for (int j = 0; j < 4; ++j)
    bfv[j] = *reinterpret_cast<const short8*>(
        &Bls[(wc * 64 + j * 16 + (lane & 15)) * 32 + (lane >> 4) * 8]);
#pragma unroll
  for (int i = 0; i < 4; ++i)
#pragma unroll
    for (int j = 0; j < 4; ++j)
      acc[i][j] = __builtin_amdgcn_mfma_f32_16x16x32_bf16(af[i], bfv[j], acc[i][j], 0, 0, 0);
}

// ---------------------------------------------------------------------------
// MFMA GEMM, global_load_lds + ping-pong LDS double buffer (BK=32/buf).
// A (M x Kp), BT (rows x Kp) zero-padded; M%128==0, Kp%64==0.
// mode 0: outf[m,n]=acc (gn<N)
// mode 1: outb[m,n]=bf16(relu(acc+D[dmap]+bias)), cols [N,ldOutb) zeroed
// mode 2: outf[m,n]=relu(acc+bias)
// ---------------------------------------------------------------------------
__global__ __launch_bounds__(256) void mfma_gemm_k(
    const ushort_t* __restrict__ A, const ushort_t* __restrict__ BT,
    const float* __restrict__ bias, const float* __restrict__ D,
    float* __restrict__ outf, ushort_t* __restrict__ outb,
    int M, int Kp, int N, int ldOutb, int mode, int base)
{
  __shared__ ushort_t Als[2][128 * 32];
  __shared__ ushort_t Bls[2][128 * 32];
  const int tid = threadIdx.x;
  const int lane = tid & 63, w = tid >> 6;
  const int wr = w >> 1, wc = w & 1;
  const int m0 = blockIdx.y * 128, n0 = blockIdx.x * 128;

  const int srow = lane >> 2;          // 0..15
  const int scol = (lane & 3) * 8;     // shorts
  const ushort_t* gA0 = A + (size_t)(m0 + w * 32 + srow) * Kp + scol;
  const ushort_t* gA1 = gA0 + (size_t)16 * Kp;
  const ushort_t* gB0 = BT + (size_t)(n0 + w * 32 + srow) * Kp + scol;
  const ushort_t* gB1 = gB0 + (size_t)16 * Kp;
  const int d0 = (w * 32) * 32, d1 = (w * 32 + 16) * 32;

#define STAGE_G(BUF, KOFF) do {                      \
    gl_lds16(gA0 + (KOFF), &Als[BUF][d0]);           \
    gl_lds16(gA1 + (KOFF), &Als[BUF][d1]);           \
    gl_lds16(gB0 + (KOFF), &Bls[BUF][d0]);           \
    gl_lds16(gB1 + (KOFF), &Bls[BUF][d1]);           \
  } while (0)

  f32x4 acc[4][4] = {};

  STAGE_G(0, 0);
  __syncthreads();                       // buf0 ready
  int kb = 0;
  const int nt2 = Kp >> 6;
  for (int i = 0; i < nt2 - 1; ++i) {
    STAGE_G(1, kb + 32);                 // prefetch while computing buf0
    gemm_comp(Als[0], Bls[0], wr, wc, lane, acc);
    __syncthreads();
    STAGE_G(0, kb + 64);
    gemm_comp(Als[1], Bls[1], wr, wc, lane, acc);
    __syncthreads();
    kb += 64;
  }
  STAGE_G(1, kb + 32);
  gemm_comp(Als[0], Bls[0], wr, wc, lane, acc);
  __syncthreads();
  gemm_comp(Als[1], Bls[1], wr, wc, lane, acc);
#undef STAGE_G

  // epilogue: C/D frag layout col=lane&15, row=(lane>>4)*4+reg
  const int crow = (lane >> 4) * 4, ccol = lane & 15;
#pragma unroll
  for (int i = 0; i < 4; ++i) {
#pragma unroll
    for (int j = 0; j < 4; ++j) {
#pragma unroll
      for (int q = 0; q < 4; ++q) {
        int gm = m0 + wr * 64 + i * 16 + crow + q;
        int gn = n0 + wc * 64 + j * 16 + ccol;
        float v = acc[i][j][q];
        if (mode == 0) {
          if (gn < N) outf[(size_t)gm * N + gn] = v;
        } else if (mode == 1) {
          if (gn < ldOutb) {
            float vv = 0.f;
            if (gn < N) {
              int g = base + gm;
              int drow = (g / 360) * 36 + (g % 36);
              vv = v + D[(size_t)drow * CAT_ + gn] + bias[gn];
              vv = vv > 0.f ? vv : 0.f;
            }
            outb[(size_t)gm * ldOutb + gn] = f2bf(vv);
          }
        } else {
          if (gn < N) {
            float vv = v + bias[gn];
            outf[(size_t)gm * N + gn] = vv > 0.f ? vv : 0.f;
          }
        }
      }
    }
  }
}

// ---------------------------------------------------------------------------
// Gated MFMA GEMM, same ping-pong staging. Tile 128x64.
// out = bf16( tanh(A@Wy+by) * leaky_relu(A@Wg+bg) )
// ---------------------------------------------------------------------------
__device__ __forceinline__ void gated_comp(
    const ushort_t* __restrict__ Als, const ushort_t* __restrict__ By,
    const ushort_t* __restrict__ Bg, int wr, int wc, int lane,
    f32x4 (&accy)[4][2], f32x4 (&accg)[4][2])
{
  short8 af[4], byf[2], bgf[2];
#pragma unroll
  for (int i = 0; i < 4; ++i)
    af[i] = *reinterpret_cast<const short8*>(
        &Als[(wr * 64 + i * 16 + (lane & 15)) * 32 + (lane >> 4) * 8]);
#pragma unroll
  for (int j = 0; j < 2; ++j) {
    int boff = (wc * 32 + j * 16 + (lane & 15)) * 32 + (lane >> 4) * 8;
    byf[j] = *reinterpret_cast<const short8*>(&By[boff]);
    bgf[j] = *reinterpret_cast<const short8*>(&Bg[boff]);
  }
#pragma unroll
  for (int i = 0; i < 4; ++i)
#pragma unroll
    for (int j = 0; j < 2; ++j) {
      accy[i][j] = __builtin_amdgcn_mfma_f32_16x16x32_bf16(af[i], byf[j], accy[i][j], 0, 0, 0);
      accg[i][j] = __builtin_amdgcn_mfma_f32_16x16x32_bf16(af[i], bgf[j], accg[i][j], 0, 0, 0);
    }
}

__global__ __launch_bounds__(256) void gated_mfma_k(
    const ushort_t* __restrict__ A,
    const ushort_t* __restrict__ ByT, const ushort_t* __restrict__ BgT,
    const float* __restrict__ by, const float* __restrict__ bg,
    ushort_t* __restrict__ out, int M, int Kp, int N)
{
  __shared__ ushort_t Als[2][128 * 32];
  __shared__ ushort_t Bls[2][2][64 * 32];
  const int tid = threadIdx.x;
  const int lane = tid & 63, w = tid >> 6;
  const int wr = w >> 1, wc = w & 1;
  const int m0 = blockIdx.y * 128, n0 = blockIdx.x * 64;

  const int srow = lane >> 2;
  const int scol = (lane & 3) * 8;
  const ushort_t* gA0 = A + (size_t)(m0 + w * 32 + srow) * Kp + scol;
  const ushort_t* gA1 = gA0 + (size_t)16 * Kp;
  const ushort_t* gBm = (w >> 1) ? BgT : ByT;
  const ushort_t* gB0 = gBm + (size_t)(n0 + (w & 1) * 32 + srow) * Kp + scol;
  const ushort_t* gB1 = gB0 + (size_t)16 * Kp;
  const int dA0 = (w * 32) * 32, dA1 = (w * 32 + 16) * 32;
  const int dB0 = ((w & 1) * 32) * 32, dB1 = ((w & 1) * 32 + 16) * 32;
  const int bm = w >> 1;

#define STAGE_W(BUF, KOFF) do {                       \
    gl_lds16(gA0 + (KOFF), &Als[BUF][dA0]);           \
    gl_lds16(gA1 + (KOFF), &Als[BUF][dA1]);           \
    gl_lds16(gB0 + (KOFF), &Bls[BUF][bm][dB0]);       \
    gl_lds16(gB1 + (KOFF), &Bls[BUF][bm][dB1]);       \
  } while (0)

  f32x4 accy[4][2] = {}, accg[4][2] = {};

  STAGE_W(0, 0);
  __syncthreads();
  int kb = 0;
  const int nt2 = Kp >> 6;
  for (int i = 0; i < nt2 - 1; ++i) {
    STAGE_W(1, kb + 32);
    gated_comp(Als[0], Bls[0][0], Bls[0][1], wr, wc, lane, accy, accg);
    __syncthreads();
    STAGE_W(0, kb + 64);
    gated_comp(Als[1], Bls[1][0], Bls[1][1], wr, wc, lane, accy, accg);
    __syncthreads();
    kb += 64;
  }
  STAGE_W(1, kb + 32);
  gated_comp(Als[0], Bls[0][0], Bls[0][1], wr, wc, lane, accy, accg);
  __syncthreads();
  gated_comp(Als[1], Bls[1][0], Bls[1][1], wr, wc, lane, accy, accg);
#undef STAGE_W

  const int crow = (lane >> 4) * 4, ccol = lane & 15;
#pragma unroll
  for (int i = 0; i < 4; ++i)
#pragma unroll
    for (int j = 0; j < 2; ++j)
#pragma unroll
      for (int q = 0; q < 4; ++q) {
        int gm = m0 + wr * 64 + i * 16 + crow + q;
        int gn = n0 + wc * 32 + j * 16 + ccol;
        if (gm >= M || gn >= N) continue;
        float y = tanhf(accy[i][j][q] + by[gn]);
        float g = accg[i][j][q] + bg[gn];
        g = (g > 0.f) ? g : 0.01f * g;
        out[(size_t)gm * N + gn] = f2bf(y * g);
      }
}

// ---------------------------------------------------------------------------
// Fused attention: scores, mask, softmax(20), PV. vt_att padded to 640 cols.
// ---------------------------------------------------------------------------
__global__ __launch_bounds__(256) void attn_fuse_k(
    const ushort_t* __restrict__ v_feat,     // (32,36,512) bf16
    const ushort_t* __restrict__ topic_feat, // (320,20,512) bf16
    const float* __restrict__ topic_raw,     // (320,20,600) f32
    const int*   __restrict__ qnp,           // (320,20)
    ushort_t* __restrict__ vt_att)           // (320,36,640) bf16, cols 600.. = 0
{
  const int b  = blockIdx.x;
  const int ib = b / NUM_R_;
  __shared__ float tr[SL_Q_][TDIM_];
  __shared__ float msk[SL_Q_];

  const int tid = threadIdx.x;
  {
    const float4* g = reinterpret_cast<const float4*>(topic_raw + (size_t)b * SL_Q_ * TDIM_);
    float4* s = reinterpret_cast<float4*>(&tr[0][0]);
    for (int i = tid; i < SL_Q_ * TDIM_ / 4; i += 256) s[i] = g[i];
  }
  if (tid < SL_Q_) msk[tid] = (float)qnp[b * SL_Q_ + tid];
  __syncthreads();

  const int wave = tid >> 6, lane = tid & 63;
  const ushort_t* tf_b = topic_feat + (size_t)b * SL_Q_ * LSTM_;

  for (int p = wave; p < NUM_P_; p += 4) {
    const ushort_t* v = v_feat + ((size_t)ib * NUM_P_ + p) * LSTM_;
    float vr[8];
#pragma unroll
    for (int k = 0; k < 8; ++k) vr[k] = bf2f(v[lane + 64 * k]);

    float sc[SL_Q_];
#pragma unroll
    for (int s = 0; s < SL_Q_; ++s) {
      const ushort_t* tfs = tf_b + (size_t)s * LSTM_;
      float acc = 0.f;
#pragma unroll
      for (int k = 0; k < 8; ++k) acc += vr[k] * bf2f(tfs[lane + 64 * k]);
#pragma unroll
      for (int off = 32; off > 0; off >>= 1) acc += __shfl_xor(acc, off, 64);
      sc[s] = acc;
    }
    float mx = -1e30f;
#pragma unroll
    for (int s = 0; s < SL_Q_; ++s) {
      float m = msk[s];
      sc[s] = sc[s] * m + (m - 1.f) * 10000.f;
      mx = fmaxf(mx, sc[s]);
    }
    float sum = 0.f;
#pragma unroll
    for (int s = 0; s < SL_Q_; ++s) { sc[s] = expf(sc[s] - mx); sum += sc[s]; }
    const float inv = 1.f / sum;

    ushort_t* outp = vt_att + ((size_t)b * NUM_P_ + p) * TDIMP_;
    for (int t = lane; t < TDIMP_; t += 64) {
      float acc = 0.f;
      if (t < TDIM_) {
#pragma unroll
        for (int s = 0; s < SL_Q_; ++s) acc += sc[s] * tr[s][t];
        acc *= inv;
      }
      outp[t] = f2bf(t < TDIM_ ? acc : 0.f);
    }
  }
}

// ---------------------------------------------------------------------------
extern "C" void kernel_launch(void* const* d_in, const int* in_sizes, int n_in,
                              void* d_out, int out_size, void* d_ws, size_t ws_size,
                              hipStream_t stream) {
  const float* img    = (const float*)d_in[0];
  const float* topic  = (const float*)d_in[1];
  const int*   qnp    = (const int*)d_in[2];
  const float* Wy_img = (const float*)d_in[3];
  const float* by_img = (const float*)d_in[4];
  const float* Wg_img = (const float*)d_in[5];
  const float* bg_img = (const float*)d_in[6];
  const float* Wy_t   = (const float*)d_in[7];
  const float* by_t   = (const float*)d_in[8];
  const float* Wg_t   = (const float*)d_in[9];
  const float* bg_t   = (const float*)d_in[10];
  const float* W1     = (const float*)d_in[11];
  const float* b1     = (const float*)d_in[12];
  const float* W2     = (const float*)d_in[13];
  const float* b2     = (const float*)d_in[14];
  float* out = (float*)d_out;

  // --- workspace (manually aliased; peak ~78.6 MB; 82.6 MB proven in R4) ---
  char* base = (char*)d_ws;
  size_t off = 0;
  auto alloc = [&](size_t bytes) {
    void* p = base + off;
    off += (bytes + 255) & ~(size_t)255;
    return p;
  };
  // region X (~37.2 MB): dead after phase D; h1c (31.0 MB) aliases it
  ushort_t* img_bf    = (ushort_t*)alloc((size_t)1152 * 2048 * 2);
  ushort_t* topic_bf  = (ushort_t*)alloc((size_t)6400 * TDIMP_ * 2);
  ushort_t* WyT_img   = (ushort_t*)alloc((size_t)512 * 2048 * 2);
  ushort_t* WgT_img   = (ushort_t*)alloc((size_t)512 * 2048 * 2);
  ushort_t* WyT_t     = (ushort_t*)alloc((size_t)512 * TDIMP_ * 2);
  ushort_t* WgT_t     = (ushort_t*)alloc((size_t)512 * TDIMP_ * 2);
  ushort_t* W1T_top   = (ushort_t*)alloc((size_t)CATP_R * 2048 * 2);
  ushort_t* v_feat    = (ushort_t*)alloc((size_t)1152 * 512 * 2);
  ushort_t* topic_ft  = (ushort_t*)alloc((size_t)6400 * 512 * 2);
  // persistent region
  ushort_t* W1T_bot   = (ushort_t*)alloc((size_t)CATP_R * TDIMP_ * 2);
  ushort_t* W2T       = (ushort_t*)alloc((size_t)2048 * CATP_K * 2);
  ushort_t* vt_att    = (ushort_t*)alloc((size_t)11520 * TDIMP_ * 2);
  float*    himg      = (float*)alloc((size_t)1152 * CAT_ * 4);
  // h1 chunk (5760 x 2688 bf16 = 31.0 MB) aliases region X
  ushort_t* h1c       = (ushort_t*)base;
  (void)ws_size;

  const dim3 blk(256);

  // --- phase A: converts + weight transposes (zero-padded) ---
  convert_bf16_k<<<dim3((1152 * 2048 / 4 + 255) / 256), blk, 0, stream>>>(
      img, img_bf, 1152 * 2048 / 4);
  convert_pad_k<<<dim3((6400 * (TDIMP_ / 4) + 255) / 256), blk, 0, stream>>>(
      topic, topic_bf, 6400, TDIM_, TDIMP_);

  transpose_pad_k<<<dim3(8, 32), blk, 0, stream>>>(Wy_img, WyT_img, 0, 2048, 512, 2048, 512);
  transpose_pad_k<<<dim3(8, 32), blk, 0, stream>>>(Wg_img, WgT_img, 0, 2048, 512, 2048, 512);
  transpose_pad_k<<<dim3(8, TDIMP_ / 64), blk, 0, stream>>>(Wy_t, WyT_t, 0, 600, 512, TDIMP_, 512);
  transpose_pad_k<<<dim3(8, TDIMP_ / 64), blk, 0, stream>>>(Wg_t, WgT_t, 0, 600, 512, TDIMP_, 512);
  transpose_pad_k<<<dim3(CATP_R / 64, 32), blk, 0, stream>>>(W1, W1T_top, 0, 2048, CAT_, 2048, CATP_R);
  transpose_pad_k<<<dim3(CATP_R / 64, TDIMP_ / 64), blk, 0, stream>>>(W1, W1T_bot, 2048, 600, CAT_, TDIMP_, CATP_R);
  transpose_pad_k<<<dim3(32, CATP_K / 64), blk, 0, stream>>>(W2, W2T, 0, CAT_, 2048, CATP_K, 2048);

  // --- phase B: gated transforms ---
  gated_mfma_k<<<dim3(8, 9), blk, 0, stream>>>(
      img_bf, WyT_img, WgT_img, by_img, bg_img, v_feat, 1152, 2048, 512);
  gated_mfma_k<<<dim3(8, 50), blk, 0, stream>>>(
      topic_bf, WyT_t, WgT_t, by_t, bg_t, topic_ft, 6400, TDIMP_, 512);

  // --- phase C: attention -> vt_att (padded 640) ---
  attn_fuse_k<<<dim3(BS_ * NUM_R_), blk, 0, stream>>>(v_feat, topic_ft, topic, qnp, vt_att);

  // --- phase D: himg = img @ W1top (f32, 1152 x 2648) ---
  mfma_gemm_k<<<dim3(21, 9), blk, 0, stream>>>(
      img_bf, W1T_top, nullptr, nullptr, himg, nullptr, 1152, 2048, CAT_, 0, 0, 0);

  // --- phases E/F: batched MLP, 2 chunks of 5760 rows ---
  for (int c = 0; c < 2; ++c) {
    const int mbase = c * 5760;
    mfma_gemm_k<<<dim3(21, 45), blk, 0, stream>>>(
        vt_att + (size_t)mbase * TDIMP_, W1T_bot, b1, himg, nullptr, h1c,
        5760, TDIMP_, CAT_, CATP_K, 1, mbase);
    mfma_gemm_k<<<dim3(16, 45), blk, 0, stream>>>(
        h1c, W2T, b2, nullptr, out + (size_t)mbase * IMG_F_, nullptr,
        5760, CATP_K, 2048, 0, 2, 0);
  }
}

// Round 10
// 571.347 us; speedup vs baseline: 3.9908x; 1.0251x over previous
//
#include <hip/hip_runtime.h>
#include <hip/hip_bf16.h>
#include <cstddef>
#include <cstdint>

#define BS_     32
#define NUM_R_  10
#define NUM_P_  36
#define SL_Q_   20
#define IMG_F_  2048
#define TDIM_   600
#define TDIMP_  640     // 600 padded to %64==0
#define LSTM_   512
#define CAT_    2648
#define CATP_K  2688    // 2648 padded to %64==0 (42 x 64)
#define CATP_R  2688    // B-row pad for 128-tiles (himg)
#define CATP_R8 2816    // B-row pad for 256-tiles (11 x 256, mode-1)

typedef unsigned short ushort_t;
typedef __attribute__((ext_vector_type(8))) short short8;
typedef __attribute__((ext_vector_type(4))) float f32x4;

__device__ __forceinline__ ushort_t f2bf(float f) {
  union { float f; unsigned int u; } v; v.f = f;
  unsigned int r = v.u + 0x7fff + ((v.u >> 16) & 1);
  return (ushort_t)(r >> 16);
}
__device__ __forceinline__ float bf2f(ushort_t u) {
  union { unsigned int u; float f; } v; v.u = ((unsigned int)u) << 16;
  return v.f;
}

// async global->LDS, 16B/lane; LDS dest = wave-uniform base + lane*16
typedef __attribute__((address_space(1))) const unsigned int as1_uint;
typedef __attribute__((address_space(3))) unsigned int as3_uint;
__device__ __forceinline__ void gl_lds16(const ushort_t* g, ushort_t* l) {
  __builtin_amdgcn_global_load_lds((as1_uint*)g, (as3_uint*)l, 16, 0, 0);
}

// ---------------------------------------------------------------------------
__global__ __launch_bounds__(256) void convert_bf16_k(
    const float* __restrict__ in, ushort_t* __restrict__ out, int n4)
{
  int i = blockIdx.x * 256 + threadIdx.x;
  if (i >= n4) return;
  float4 v = reinterpret_cast<const float4*>(in)[i];
  ushort4 o;
  o.x = f2bf(v.x); o.y = f2bf(v.y); o.z = f2bf(v.z); o.w = f2bf(v.w);
  reinterpret_cast<ushort4*>(out)[i] = o;
}

__global__ __launch_bounds__(256) void convert_pad_k(
    const float* __restrict__ in, ushort_t* __restrict__ out,
    int rows, int C, int Cp)
{
  int npc = Cp >> 2;
  int i = blockIdx.x * 256 + threadIdx.x;
  if (i >= rows * npc) return;
  int row = i / npc, c4 = (i - row * npc) << 2;
  ushort4 o = make_ushort4(0, 0, 0, 0);
  if (c4 < C) {
    float4 v = *reinterpret_cast<const float4*>(&in[(size_t)row * C + c4]);
    o.x = f2bf(v.x); o.y = f2bf(v.y); o.z = f2bf(v.z); o.w = f2bf(v.w);
  }
  *reinterpret_cast<ushort4*>(&out[(size_t)row * Cp + c4]) = o;
}

__global__ __launch_bounds__(256) void transpose_pad_k(
    const float* __restrict__ in, ushort_t* __restrict__ out,
    int r0, int R, int C, int Rp, int Cp)
{
  __shared__ float tile[64][65];
  const int t = threadIdx.x;
  const int lc = t & 63, g = t >> 6;
  const int rbase = blockIdx.y * 64, cbase = blockIdx.x * 64;
#pragma unroll
  for (int i = 0; i < 16; ++i) {
    int lr = g + 4 * i;
    int rr = rbase + lr, cc = cbase + lc;
    tile[lr][lc] = (rr < R && cc < C) ? in[(size_t)(r0 + rr) * C + cc] : 0.f;
  }
  __syncthreads();
#pragma unroll
  for (int i = 0; i < 16; ++i) {
    int wr2 = g + 4 * i;
    int oc = cbase + wr2, orr = rbase + lc;
    if (oc < Cp && orr < Rp)
      out[(size_t)oc * Rp + orr] = f2bf(tile[lc][wr2]);
  }
}

// ---------------------------------------------------------------------------
// 2-phase 128x128 kernel (validated) — kept for himg (mode 0 only here).
// ---------------------------------------------------------------------------
__device__ __forceinline__ void gemm_comp(
    const ushort_t* __restrict__ Als, const ushort_t* __restrict__ Bls,
    int wr, int wc, int lane, f32x4 (&acc)[4][4])
{
  short8 af[4], bfv[4];
#pragma unroll
  for (int i = 0; i < 4; ++i)
    af[i] = *reinterpret_cast<const short8*>(
        &Als[(wr * 64 + i * 16 + (lane & 15)) * 32 + (lane >> 4) * 8]);
#pragma unroll
  for (int j = 0; j < 4; ++j)
    bfv[j] = *reinterpret_cast<const short8*>(
        &Bls[(wc * 64 + j * 16 + (lane & 15)) * 32 + (lane >> 4) * 8]);
#pragma unroll
  for (int i = 0; i < 4; ++i)
#pragma unroll
    for (int j = 0; j < 4; ++j)
      acc[i][j] = __builtin_amdgcn_mfma_f32_16x16x32_bf16(af[i], bfv[j], acc[i][j], 0, 0, 0);
}

__global__ __launch_bounds__(256) void mfma_gemm_k(
    const ushort_t* __restrict__ A, const ushort_t* __restrict__ BT,
    float* __restrict__ outf, int M, int Kp, int N)
{
  __shared__ ushort_t Als[2][128 * 32];
  __shared__ ushort_t Bls[2][128 * 32];
  const int tid = threadIdx.x;
  const int lane = tid & 63, w = tid >> 6;
  const int wr = w >> 1, wc = w & 1;
  const int m0 = blockIdx.y * 128, n0 = blockIdx.x * 128;

  const int srow = lane >> 2;
  const int scol = (lane & 3) * 8;
  const ushort_t* gA0 = A + (size_t)(m0 + w * 32 + srow) * Kp + scol;
  const ushort_t* gA1 = gA0 + (size_t)16 * Kp;
  const ushort_t* gB0 = BT + (size_t)(n0 + w * 32 + srow) * Kp + scol;
  const ushort_t* gB1 = gB0 + (size_t)16 * Kp;
  const int d0 = (w * 32) * 32, d1 = (w * 32 + 16) * 32;

#define STAGE_G(BUF, KOFF) do {                      \
    gl_lds16(gA0 + (KOFF), &Als[BUF][d0]);           \
    gl_lds16(gA1 + (KOFF), &Als[BUF][d1]);           \
    gl_lds16(gB0 + (KOFF), &Bls[BUF][d0]);           \
    gl_lds16(gB1 + (KOFF), &Bls[BUF][d1]);           \
  } while (0)

  f32x4 acc[4][4] = {};
  STAGE_G(0, 0);
  __syncthreads();
  int kb = 0;
  const int nt2 = Kp >> 6;
  for (int i = 0; i < nt2 - 1; ++i) {
    STAGE_G(1, kb + 32);
    gemm_comp(Als[0], Bls[0], wr, wc, lane, acc);
    __syncthreads();
    STAGE_G(0, kb + 64);
    gemm_comp(Als[1], Bls[1], wr, wc, lane, acc);
    __syncthreads();
    kb += 64;
  }
  STAGE_G(1, kb + 32);
  gemm_comp(Als[0], Bls[0], wr, wc, lane, acc);
  __syncthreads();
  gemm_comp(Als[1], Bls[1], wr, wc, lane, acc);
#undef STAGE_G

  const int crow = (lane >> 4) * 4, ccol = lane & 15;
#pragma unroll
  for (int i = 0; i < 4; ++i)
#pragma unroll
    for (int j = 0; j < 4; ++j)
#pragma unroll
      for (int q = 0; q < 4; ++q) {
        int gm = m0 + wr * 64 + i * 16 + crow + q;
        int gn = n0 + wc * 64 + j * 16 + ccol;
        if (gm < M && gn < N) outf[(size_t)gm * N + gn] = acc[i][j][q];
      }
}

// ---------------------------------------------------------------------------
// 8-phase 256x256 kernel (T3+T4 counted vmcnt, T2 swizzle, T5 setprio).
// 8 waves (512 thr) as 2M x 4N; per-wave 128x64 out; BK=64, slots
// {A-k0,B-k0,A-k1,B-k1} of 16KB, double-buffered (128KB dynamic LDS).
// Stage slot j of tile T+1 during phase j of tile T; vmcnt(6) per phase
// guarantees stages <= p-3 landed; phase j consumes slots <= j+1 (safe).
// LDS swizzle: phys c2 = ((row&1)<<2 | lg) ^ ((row>>1)&7); source is
// inverse-permuted so linear gl_lds writes land swizzled (rule #21).
// mode 1: outb = bf16(relu(acc + D[dmap(base+gm)] + bias)), pad cols zeroed
// mode 2: outf = relu(acc + bias)
// ---------------------------------------------------------------------------
__global__ __launch_bounds__(512, 2) void mfma_gemm8_k(
    const ushort_t* __restrict__ A, const ushort_t* __restrict__ BT,
    const float* __restrict__ bias, const float* __restrict__ D,
    float* __restrict__ outf, ushort_t* __restrict__ outb,
    int M, int Kp, int N, int ldOutb, int mode, int base)
{
  extern __shared__ ushort_t lds8[];     // 2 bufs x 4 slots x 8192 shorts
  const int tid = threadIdx.x;
  const int lane = tid & 63, w = tid >> 6;
  const int wr = w >> 2, wc = w & 3;     // 2M x 4N waves
  const int m0 = blockIdx.y * 256, n0 = blockIdx.x * 256;
  const int r15 = lane & 15, lg = lane >> 4;

  // staging source coords (inverse-swizzled):
  const int pr = lane >> 3, hh = lane & 7;
  const int cc = hh ^ pr;
  const int srow_l = (pr << 1) | (cc >> 2);   // 0..15 within a 16-row issue
  const int scol_l = (cc & 3) << 3;           // 0,8,16,24 shorts within 32

  // stage slot s (0:A-k0 1:B-k0 2:A-k1 3:B-k1) of K-tile kt into buffer b
#define STAGE8(b_, s_, kt_) do {                                             \
    const ushort_t* src_ = ((s_) & 1) ? BT : A;                              \
    const int rowb_ = ((s_) & 1) ? n0 : m0;                                  \
    const int kcol_ = (kt_) * 64 + ((s_) >> 1) * 32 + scol_l;                \
    ushort_t* dst_ = &lds8[(b_) * 32768 + (s_) * 8192];                      \
    _Pragma("unroll")                                                        \
    for (int i_ = 0; i_ < 2; ++i_) {                                         \
      int grow_ = rowb_ + w * 32 + i_ * 16 + srow_l;                         \
      gl_lds16(src_ + (size_t)grow_ * Kp + kcol_,                            \
               &dst_[(w * 32 + i_ * 16) * 32]);                              \
    }                                                                        \
  } while (0)

  // swizzled LDS read address (shorts)
#define LDS_RD(b_, s_, row_) (*reinterpret_cast<const short8*>(              \
    &lds8[(b_) * 32768 + (s_) * 8192 + ((row_) >> 1) * 64 +                  \
          (((((row_) & 1) << 2) | lg) ^ (((row_) >> 1) & 7)) * 8]))

  f32x4 acc[8][4] = {};
  short8 aF[8], bF[2];
  const int NT = Kp >> 6;

  // prologue: stage tile 0 into buf 0
  STAGE8(0, 0, 0); STAGE8(0, 1, 0); STAGE8(0, 2, 0); STAGE8(0, 3, 0);

#define PHASE_WAIT() do {                                   \
    asm volatile("s_waitcnt vmcnt(6)" ::: "memory");        \
    __builtin_amdgcn_s_barrier();                           \
    __builtin_amdgcn_sched_barrier(0);                      \
  } while (0)

#define LOAD_A(b_, ks_) do {                                               \
    _Pragma("unroll")                                                      \
    for (int mf_ = 0; mf_ < 8; ++mf_)                                      \
      aF[mf_] = LDS_RD(b_, (ks_) * 2, wr * 128 + mf_ * 16 + r15);          \
  } while (0)

#define LOAD_B(b_, ks_, nfb_) do {                                         \
    bF[0] = LDS_RD(b_, (ks_) * 2 + 1, wc * 64 + (nfb_) * 16 + r15);        \
    bF[1] = LDS_RD(b_, (ks_) * 2 + 1, wc * 64 + ((nfb_) + 1) * 16 + r15);  \
  } while (0)

#define DO_MFMA(nfb_) do {                                                 \
    __builtin_amdgcn_s_setprio(1);                                         \
    _Pragma("unroll")                                                      \
    for (int mf_ = 0; mf_ < 8; ++mf_) {                                    \
      acc[mf_][(nfb_)] = __builtin_amdgcn_mfma_f32_16x16x32_bf16(          \
          aF[mf_], bF[0], acc[mf_][(nfb_)], 0, 0, 0);                      \
      acc[mf_][(nfb_) + 1] = __builtin_amdgcn_mfma_f32_16x16x32_bf16(      \
          aF[mf_], bF[1], acc[mf_][(nfb_) + 1], 0, 0, 0);                  \
    }                                                                      \
    __builtin_amdgcn_s_setprio(0);                                         \
    __builtin_amdgcn_sched_barrier(0);                                     \
  } while (0)

  for (int T = 0; T < NT - 1; ++T) {
    const int b = T & 1, nb = b ^ 1;
    // j=0: stage A-k0(T+1); compute ks0 nf{0,1}
    STAGE8(nb, 0, T + 1);
    PHASE_WAIT();
    LOAD_A(b, 0); LOAD_B(b, 0, 0);
    DO_MFMA(0);
    // j=1: stage B-k0(T+1); compute ks0 nf{2,3} (aF reused)
    STAGE8(nb, 1, T + 1);
    PHASE_WAIT();
    LOAD_B(b, 0, 2);
    DO_MFMA(2);
    // j=2: stage A-k1(T+1); compute ks1 nf{0,1}
    STAGE8(nb, 2, T + 1);
    PHASE_WAIT();
    LOAD_A(b, 1); LOAD_B(b, 1, 0);
    DO_MFMA(0);
    // j=3: stage B-k1(T+1); compute ks1 nf{2,3}
    STAGE8(nb, 3, T + 1);
    PHASE_WAIT();
    LOAD_B(b, 1, 2);
    DO_MFMA(2);
  }
  // epilogue tile NT-1: drain, then 4 groups, no staging
  {
    asm volatile("s_waitcnt vmcnt(0)" ::: "memory");
    __builtin_amdgcn_s_barrier();
    __builtin_amdgcn_sched_barrier(0);
    const int b = (NT - 1) & 1;
    LOAD_A(b, 0); LOAD_B(b, 0, 0); DO_MFMA(0);
    LOAD_B(b, 0, 2);                DO_MFMA(2);
    LOAD_A(b, 1); LOAD_B(b, 1, 0); DO_MFMA(0);
    LOAD_B(b, 1, 2);                DO_MFMA(2);
  }
#undef STAGE8
#undef PHASE_WAIT
#undef LOAD_A
#undef LOAD_B
#undef DO_MFMA
#undef LDS_RD

  // epilogue write: C/D frag layout col=lane&15, row=(lane>>4)*4+q
  const int crow = lg * 4;
#pragma unroll
  for (int mf = 0; mf < 8; ++mf) {
#pragma unroll
    for (int nf = 0; nf < 4; ++nf) {
#pragma unroll
      for (int q = 0; q < 4; ++q) {
        int gm = m0 + wr * 128 + mf * 16 + crow + q;
        int gn = n0 + wc * 64 + nf * 16 + r15;
        if (gm >= M) continue;
        float v = acc[mf][nf][q];
        if (mode == 1) {
          if (gn < ldOutb) {
            float vv = 0.f;
            if (gn < N) {
              int g = base + gm;
              int drow = (g / 360) * 36 + (g % 36);
              vv = v + D[(size_t)drow * CAT_ + gn] + bias[gn];
              vv = vv > 0.f ? vv : 0.f;
            }
            outb[(size_t)gm * ldOutb + gn] = f2bf(vv);
          }
        } else {
          if (gn < N) {
            float vv = v + bias[gn];
            outf[(size_t)gm * N + gn] = vv > 0.f ? vv : 0.f;
          }
        }
      }
    }
  }
}

// ---------------------------------------------------------------------------
// Gated MFMA GEMM (2-phase ping-pong, validated) — unchanged.
// ---------------------------------------------------------------------------
__device__ __forceinline__ void gated_comp(
    const ushort_t* __restrict__ Als, const ushort_t* __restrict__ By,
    const ushort_t* __restrict__ Bg, int wr, int wc, int lane,
    f32x4 (&accy)[4][2], f32x4 (&accg)[4][2])
{
  short8 af[4], byf[2], bgf[2];
#pragma unroll
  for (int i = 0; i < 4; ++i)
    af[i] = *reinterpret_cast<const short8*>(
        &Als[(wr * 64 + i * 16 + (lane & 15)) * 32 + (lane >> 4) * 8]);
#pragma unroll
  for (int j = 0; j < 2; ++j) {
    int boff = (wc * 32 + j * 16 + (lane & 15)) * 32 + (lane >> 4) * 8;
    byf[j] = *reinterpret_cast<const short8*>(&By[boff]);
    bgf[j] = *reinterpret_cast<const short8*>(&Bg[boff]);
  }
#pragma unroll
  for (int i = 0; i < 4; ++i)
#pragma unroll
    for (int j = 0; j < 2; ++j) {
      accy[i][j] = __builtin_amdgcn_mfma_f32_16x16x32_bf16(af[i], byf[j], accy[i][j], 0, 0, 0);
      accg[i][j] = __builtin_amdgcn_mfma_f32_16x16x32_bf16(af[i], bgf[j], accg[i][j], 0, 0, 0);
    }
}

__global__ __launch_bounds__(256) void gated_mfma_k(
    const ushort_t* __restrict__ A,
    const ushort_t* __restrict__ ByT, const ushort_t* __restrict__ BgT,
    const float* __restrict__ by, const float* __restrict__ bg,
    ushort_t* __restrict__ out, int M, int Kp, int N)
{
  __shared__ ushort_t Als[2][128 * 32];
  __shared__ ushort_t Bls[2][2][64 * 32];
  const int tid = threadIdx.x;
  const int lane = tid & 63, w = tid >> 6;
  const int wr = w >> 1, wc = w & 1;
  const int m0 = blockIdx.y * 128, n0 = blockIdx.x * 64;

  const int srow = lane >> 2;
  const int scol = (lane & 3) * 8;
  const ushort_t* gA0 = A + (size_t)(m0 + w * 32 + srow) * Kp + scol;
  const ushort_t* gA1 = gA0 + (size_t)16 * Kp;
  const ushort_t* gBm = (w >> 1) ? BgT : ByT;
  const ushort_t* gB0 = gBm + (size_t)(n0 + (w & 1) * 32 + srow) * Kp + scol;
  const ushort_t* gB1 = gB0 + (size_t)16 * Kp;
  const int dA0 = (w * 32) * 32, dA1 = (w * 32 + 16) * 32;
  const int dB0 = ((w & 1) * 32) * 32, dB1 = ((w & 1) * 32 + 16) * 32;
  const int bm = w >> 1;

#define STAGE_W(BUF, KOFF) do {                       \
    gl_lds16(gA0 + (KOFF), &Als[BUF][dA0]);           \
    gl_lds16(gA1 + (KOFF), &Als[BUF][dA1]);           \
    gl_lds16(gB0 + (KOFF), &Bls[BUF][bm][dB0]);       \
    gl_lds16(gB1 + (KOFF), &Bls[BUF][bm][dB1]);       \
  } while (0)

  f32x4 accy[4][2] = {}, accg[4][2] = {};
  STAGE_W(0, 0);
  __syncthreads();
  int kb = 0;
  const int nt2 = Kp >> 6;
  for (int i = 0; i < nt2 - 1; ++i) {
    STAGE_W(1, kb + 32);
    gated_comp(Als[0], Bls[0][0], Bls[0][1], wr, wc, lane, accy, accg);
    __syncthreads();
    STAGE_W(0, kb + 64);
    gated_comp(Als[1], Bls[1][0], Bls[1][1], wr, wc, lane, accy, accg);
    __syncthreads();
    kb += 64;
  }
  STAGE_W(1, kb + 32);
  gated_comp(Als[0], Bls[0][0], Bls[0][1], wr, wc, lane, accy, accg);
  __syncthreads();
  gated_comp(Als[1], Bls[1][0], Bls[1][1], wr, wc, lane, accy, accg);
#undef STAGE_W

  const int crow = (lane >> 4) * 4, ccol = lane & 15;
#pragma unroll
  for (int i = 0; i < 4; ++i)
#pragma unroll
    for (int j = 0; j < 2; ++j)
#pragma unroll
      for (int q = 0; q < 4; ++q) {
        int gm = m0 + wr * 64 + i * 16 + crow + q;
        int gn = n0 + wc * 32 + j * 16 + ccol;
        if (gm >= M || gn >= N) continue;
        float y = tanhf(accy[i][j][q] + by[gn]);
        float g = accg[i][j][q] + bg[gn];
        g = (g > 0.f) ? g : 0.01f * g;
        out[(size_t)gm * N + gn] = f2bf(y * g);
      }
}

// ---------------------------------------------------------------------------
// Fused attention — unchanged.
// ---------------------------------------------------------------------------
__global__ __launch_bounds__(256) void attn_fuse_k(
    const ushort_t* __restrict__ v_feat,
    const ushort_t* __restrict__ topic_feat,
    const float* __restrict__ topic_raw,
    const int*   __restrict__ qnp,
    ushort_t* __restrict__ vt_att)
{
  const int b  = blockIdx.x;
  const int ib = b / NUM_R_;
  __shared__ float tr[SL_Q_][TDIM_];
  __shared__ float msk[SL_Q_];

  const int tid = threadIdx.x;
  {
    const float4* g = reinterpret_cast<const float4*>(topic_raw + (size_t)b * SL_Q_ * TDIM_);
    float4* s = reinterpret_cast<float4*>(&tr[0][0]);
    for (int i = tid; i < SL_Q_ * TDIM_ / 4; i += 256) s[i] = g[i];
  }
  if (tid < SL_Q_) msk[tid] = (float)qnp[b * SL_Q_ + tid];
  __syncthreads();

  const int wave = tid >> 6, lane = tid & 63;
  const ushort_t* tf_b = topic_feat + (size_t)b * SL_Q_ * LSTM_;

  for (int p = wave; p < NUM_P_; p += 4) {
    const ushort_t* v = v_feat + ((size_t)ib * NUM_P_ + p) * LSTM_;
    float vr[8];
#pragma unroll
    for (int k = 0; k < 8; ++k) vr[k] = bf2f(v[lane + 64 * k]);

    float sc[SL_Q_];
#pragma unroll
    for (int s = 0; s < SL_Q_; ++s) {
      const ushort_t* tfs = tf_b + (size_t)s * LSTM_;
      float acc = 0.f;
#pragma unroll
      for (int k = 0; k < 8; ++k) acc += vr[k] * bf2f(tfs[lane + 64 * k]);
#pragma unroll
      for (int off = 32; off > 0; off >>= 1) acc += __shfl_xor(acc, off, 64);
      sc[s] = acc;
    }
    float mx = -1e30f;
#pragma unroll
    for (int s = 0; s < SL_Q_; ++s) {
      float m = msk[s];
      sc[s] = sc[s] * m + (m - 1.f) * 10000.f;
      mx = fmaxf(mx, sc[s]);
    }
    float sum = 0.f;
#pragma unroll
    for (int s = 0; s < SL_Q_; ++s) { sc[s] = expf(sc[s] - mx); sum += sc[s]; }
    const float inv = 1.f / sum;

    ushort_t* outp = vt_att + ((size_t)b * NUM_P_ + p) * TDIMP_;
    for (int t = lane; t < TDIMP_; t += 64) {
      float acc = 0.f;
      if (t < TDIM_) {
#pragma unroll
        for (int s = 0; s < SL_Q_; ++s) acc += sc[s] * tr[s][t];
        acc *= inv;
      }
      outp[t] = f2bf(t < TDIM_ ? acc : 0.f);
    }
  }
}

// ---------------------------------------------------------------------------
extern "C" void kernel_launch(void* const* d_in, const int* in_sizes, int n_in,
                              void* d_out, int out_size, void* d_ws, size_t ws_size,
                              hipStream_t stream) {
  const float* img    = (const float*)d_in[0];
  const float* topic  = (const float*)d_in[1];
  const int*   qnp    = (const int*)d_in[2];
  const float* Wy_img = (const float*)d_in[3];
  const float* by_img = (const float*)d_in[4];
  const float* Wg_img = (const float*)d_in[5];
  const float* bg_img = (const float*)d_in[6];
  const float* Wy_t   = (const float*)d_in[7];
  const float* by_t   = (const float*)d_in[8];
  const float* Wg_t   = (const float*)d_in[9];
  const float* bg_t   = (const float*)d_in[10];
  const float* W1     = (const float*)d_in[11];
  const float* b1     = (const float*)d_in[12];
  const float* W2     = (const float*)d_in[13];
  const float* b2     = (const float*)d_in[14];
  float* out = (float*)d_out;

  // --- workspace (aliased; peak ~78.9 MB; 82.6 proven) ---
  char* base = (char*)d_ws;
  size_t off = 0;
  auto alloc = [&](size_t bytes) {
    void* p = base + off;
    off += (bytes + 255) & ~(size_t)255;
    return p;
  };
  // region X (~37.2 MB): dead after phase D; h1c (5888 x 2688 = 31.7 MB) aliases
  ushort_t* img_bf    = (ushort_t*)alloc((size_t)1152 * 2048 * 2);
  ushort_t* topic_bf  = (ushort_t*)alloc((size_t)6400 * TDIMP_ * 2);
  ushort_t* WyT_img   = (ushort_t*)alloc((size_t)512 * 2048 * 2);
  ushort_t* WgT_img   = (ushort_t*)alloc((size_t)512 * 2048 * 2);
  ushort_t* WyT_t     = (ushort_t*)alloc((size_t)512 * TDIMP_ * 2);
  ushort_t* WgT_t     = (ushort_t*)alloc((size_t)512 * TDIMP_ * 2);
  ushort_t* W1T_top   = (ushort_t*)alloc((size_t)CATP_R * 2048 * 2);
  ushort_t* v_feat    = (ushort_t*)alloc((size_t)1152 * 512 * 2);
  ushort_t* topic_ft  = (ushort_t*)alloc((size_t)6400 * 512 * 2);
  // persistent
  ushort_t* W1T_bot   = (ushort_t*)alloc((size_t)CATP_R8 * TDIMP_ * 2);
  ushort_t* W2T       = (ushort_t*)alloc((size_t)2048 * CATP_K * 2);
  ushort_t* vt_att    = (ushort_t*)alloc((size_t)(11520 + 128) * TDIMP_ * 2); // +128 pad rows (M-tile overread)
  float*    himg      = (float*)alloc((size_t)1152 * CAT_ * 4);
  ushort_t* h1c       = (ushort_t*)base;   // 5888 rows x 2688 cols
  (void)ws_size;

  const dim3 blk(256);

  // --- phase A: converts + weight transposes (zero-padded) ---
  convert_bf16_k<<<dim3((1152 * 2048 / 4 + 255) / 256), blk, 0, stream>>>(
      img, img_bf, 1152 * 2048 / 4);
  convert_pad_k<<<dim3((6400 * (TDIMP_ / 4) + 255) / 256), blk, 0, stream>>>(
      topic, topic_bf, 6400, TDIM_, TDIMP_);

  transpose_pad_k<<<dim3(8, 32), blk, 0, stream>>>(Wy_img, WyT_img, 0, 2048, 512, 2048, 512);
  transpose_pad_k<<<dim3(8, 32), blk, 0, stream>>>(Wg_img, WgT_img, 0, 2048, 512, 2048, 512);
  transpose_pad_k<<<dim3(8, TDIMP_ / 64), blk, 0, stream>>>(Wy_t, WyT_t, 0, 600, 512, TDIMP_, 512);
  transpose_pad_k<<<dim3(8, TDIMP_ / 64), blk, 0, stream>>>(Wg_t, WgT_t, 0, 600, 512, TDIMP_, 512);
  transpose_pad_k<<<dim3(CATP_R / 64, 32), blk, 0, stream>>>(W1, W1T_top, 0, 2048, CAT_, 2048, CATP_R);
  transpose_pad_k<<<dim3(CATP_R8 / 64, TDIMP_ / 64), blk, 0, stream>>>(W1, W1T_bot, 2048, 600, CAT_, TDIMP_, CATP_R8);
  transpose_pad_k<<<dim3(32, CATP_K / 64), blk, 0, stream>>>(W2, W2T, 0, CAT_, 2048, CATP_K, 2048);

  // --- phase B: gated transforms ---
  gated_mfma_k<<<dim3(8, 9), blk, 0, stream>>>(
      img_bf, WyT_img, WgT_img, by_img, bg_img, v_feat, 1152, 2048, 512);
  gated_mfma_k<<<dim3(8, 50), blk, 0, stream>>>(
      topic_bf, WyT_t, WgT_t, by_t, bg_t, topic_ft, 6400, TDIMP_, 512);

  // --- phase C: attention ---
  attn_fuse_k<<<dim3(BS_ * NUM_R_), blk, 0, stream>>>(v_feat, topic_ft, topic, qnp, vt_att);

  // --- phase D: himg = img @ W1top (2-phase 128^2 kernel) ---
  mfma_gemm_k<<<dim3(21, 9), blk, 0, stream>>>(
      img_bf, W1T_top, himg, 1152, 2048, CAT_);

  // --- phases E/F: batched MLP (8-phase 256^2 kernel), 2 chunks of 5760 ---
  for (int c = 0; c < 2; ++c) {
    const int mbase = c * 5760;
    mfma_gemm8_k<<<dim3(11, 23), dim3(512), 131072, stream>>>(
        vt_att + (size_t)mbase * TDIMP_, W1T_bot, b1, himg, nullptr, h1c,
        5760, TDIMP_, CAT_, CATP_K, 1, mbase);
    mfma_gemm8_k<<<dim3(8, 23), dim3(512), 131072, stream>>>(
        h1c, W2T, b2, nullptr, out + (size_t)mbase * IMG_F_, nullptr,
        5760, CATP_K, 2048, 0, 2, 0);
  }
}